// Round 6
// baseline (280.803 us; speedup 1.0000x reference)
//
#include <hip/hip_runtime.h>
#include <hip/hip_bf16.h>

#define NEG_SLOPE 0.2f

typedef _Float16 half8 __attribute__((ext_vector_type(8)));
typedef _Float16 half4v __attribute__((ext_vector_type(4)));
typedef _Float16 half2v __attribute__((ext_vector_type(2)));
typedef float floatx4 __attribute__((ext_vector_type(4)));
typedef float floatx2 __attribute__((ext_vector_type(2)));

// ---------------------------------------------------------------- CSR build
__global__ void k_hist(const int* __restrict__ dst, int E, int n, int* __restrict__ deg) {
    int e = blockIdx.x * blockDim.x + threadIdx.x;
    int ET = E + n;
    if (e >= ET) return;
    int d = (e < E) ? dst[e] : (e - E);   // self-loops appended
    atomicAdd(&deg[d], 1);
}

__global__ void k_scan(const int* __restrict__ deg, int* __restrict__ rowptr,
                       int* __restrict__ cursor, int n) {
    __shared__ int part[256];
    int t = threadIdx.x;
    int chunk = (n + 255) / 256;
    int s0 = t * chunk, s1 = min(s0 + chunk, n);
    int s = 0;
    for (int i = s0; i < s1; ++i) s += deg[i];
    part[t] = s;
    __syncthreads();
    for (int off = 1; off < 256; off <<= 1) {
        int v = (t >= off) ? part[t - off] : 0;
        __syncthreads();
        part[t] += v;
        __syncthreads();
    }
    int run = (t == 0) ? 0 : part[t - 1];
    for (int i = s0; i < s1; ++i) { rowptr[i] = run; cursor[i] = run; run += deg[i]; }
    if (t == 255) rowptr[n] = run;
}

__global__ void k_scatter(const int* __restrict__ src, const int* __restrict__ dst,
                          int E, int n, int* __restrict__ cursor,
                          int* __restrict__ csr_src, int* __restrict__ csr_dst) {
    int e = blockIdx.x * blockDim.x + threadIdx.x;
    int ET = E + n;
    if (e >= ET) return;
    int s = (e < E) ? src[e] : (e - E);
    int d = (e < E) ? dst[e] : (e - E);
    int pos = atomicAdd(&cursor[d], 1);
    csr_src[pos] = s;
    csr_dst[pos] = d;
}

// ------------------------------------------------------------- conversions
__global__ void k_f2h8(const float* __restrict__ in, _Float16* __restrict__ out, int n8) {
    int i = blockIdx.x * 256 + threadIdx.x;
    if (i >= n8) return;
    const float4* p = (const float4*)in + (size_t)i * 2;
    float4 a = p[0], b = p[1];
    _Float16 h[8] = {(_Float16)a.x, (_Float16)a.y, (_Float16)a.z, (_Float16)a.w,
                     (_Float16)b.x, (_Float16)b.y, (_Float16)b.z, (_Float16)b.w};
    *(uint4*)(out + (size_t)i * 8) = *(const uint4*)h;
}

// W[R][C] fp32 -> Wt[C][R] fp16
__global__ void k_transpose_h(const float* __restrict__ W, _Float16* __restrict__ Wt,
                              int R, int C) {
    int i = blockIdx.x * 256 + threadIdx.x;
    if (i >= R * C) return;
    int c = i / R, r = i % R;
    Wt[i] = (_Float16)W[(size_t)r * C + c];
}

// ------------------------------------------------------------ fp16 MFMA GEMM
__device__ __forceinline__ void gload_lds16(const _Float16* g, _Float16* l) {
    __builtin_amdgcn_global_load_lds((const __attribute__((address_space(1))) void*)g,
                                     (__attribute__((address_space(3))) void*)l,
                                     16, 0, 0);
}

template <typename OutT>
__global__ __launch_bounds__(256) void k_hgemm(const _Float16* __restrict__ A,
                                               const _Float16* __restrict__ Bt,
                                               OutT* __restrict__ C,
                                               int M, int N, int K) {
    __shared__ _Float16 lds[2 * 8192];       // [buf][A:4096|B:4096] elems (32KB)
    int t = threadIdx.x;
    int lane = t & 63, w = t >> 6;
    int wr = w >> 1, wc = w & 1;
    int lrow = lane & 15, lko = lane >> 4;
    int row0 = blockIdx.y * 128, col0 = blockIdx.x * 128;

    int sr = t & 127;
    int sko = t >> 7;
    int agr = row0 + sr; if (agr >= M) agr = M - 1;
    const _Float16* aRow = A + (size_t)agr * K;
    const _Float16* bRow = Bt + (size_t)(col0 + sr) * K;

    floatx4 acc[4][4] = {};

    int nk = K >> 5;
#pragma unroll
    for (int s = 0; s < 2; ++s) {
        int ko = s * 2 + sko;
        gload_lds16(aRow + ko * 8, lds + s * 2048 + t * 8);
        gload_lds16(bRow + ko * 8, lds + 4096 + s * 2048 + t * 8);
    }
    __syncthreads();

    for (int ks = 0; ks < nk; ++ks) {
        int buf = ks & 1;
        if (ks + 1 < nk) {
            int kt = (ks + 1) << 5;
            _Float16* dstb = lds + (buf ^ 1) * 8192;
#pragma unroll
            for (int s = 0; s < 2; ++s) {
                int ko = s * 2 + sko;
                gload_lds16(aRow + kt + ko * 8, dstb + s * 2048 + t * 8);
                gload_lds16(bRow + kt + ko * 8, dstb + 4096 + s * 2048 + t * 8);
            }
        }
        const _Float16* base = lds + buf * 8192 + lko * 1024;
        half8 af[4], bf[4];
#pragma unroll
        for (int mi = 0; mi < 4; ++mi)
            af[mi] = *(const half8*)(base + (wr * 64 + mi * 16 + lrow) * 8);
#pragma unroll
        for (int ni = 0; ni < 4; ++ni)
            bf[ni] = *(const half8*)(base + 4096 + (wc * 64 + ni * 16 + lrow) * 8);
#pragma unroll
        for (int mi = 0; mi < 4; ++mi)
#pragma unroll
            for (int ni = 0; ni < 4; ++ni)
                acc[mi][ni] = __builtin_amdgcn_mfma_f32_16x16x32_f16(
                    af[mi], bf[ni], acc[mi][ni], 0, 0, 0);
        __syncthreads();
    }

#pragma unroll
    for (int mi = 0; mi < 4; ++mi) {
        int rb = row0 + wr * 64 + mi * 16 + lko * 4;
#pragma unroll
        for (int ni = 0; ni < 4; ++ni) {
            int col = col0 + wc * 64 + ni * 16 + lrow;
#pragma unroll
            for (int j = 0; j < 4; ++j) {
                int row = rb + j;
                if (row < M) C[(size_t)row * N + col] = (OutT)acc[mi][ni][j];
            }
        }
    }
}

// ------------------------------------------------------- attention logit dots
template <int H, int C>
__global__ __launch_bounds__(256) void k_att(const _Float16* __restrict__ h,
                      const float* __restrict__ as, const float* __restrict__ ad,
                      float* __restrict__ al_s, float* __restrict__ al_d, int n) {
    int wid = (blockIdx.x * blockDim.x + threadIdx.x) >> 6;
    int lane = threadIdx.x & 63;
    if (wid >= n * H) return;
    int node = wid / H, hh = wid % H;
    const _Float16* hp = h + (size_t)node * H * C + hh * C;
    const float* sp = as + hh * C;
    const float* dp = ad + hh * C;
    float aS, aD;
    {
        half4v v = *(const half4v*)(hp + lane * 4);
        float4 a = *(const float4*)(sp + lane * 4);
        float4 d = *(const float4*)(dp + lane * 4);
        float f0 = (float)v[0], f1 = (float)v[1], f2 = (float)v[2], f3 = (float)v[3];
        aS = f0 * a.x + f1 * a.y + f2 * a.z + f3 * a.w;
        aD = f0 * d.x + f1 * d.y + f2 * d.z + f3 * d.w;
    }
    if constexpr (C == 384) {
        half2v v = *(const half2v*)(hp + 256 + lane * 2);
        floatx2 a = *(const floatx2*)(sp + 256 + lane * 2);
        floatx2 d = *(const floatx2*)(dp + 256 + lane * 2);
        aS += (float)v[0] * a[0] + (float)v[1] * a[1];
        aD += (float)v[0] * d[0] + (float)v[1] * d[1];
    }
#pragma unroll
    for (int off = 32; off; off >>= 1) {
        aS += __shfl_xor(aS, off);
        aD += __shfl_xor(aD, off);
    }
    if (lane == 0) { al_s[wid] = aS; al_d[wid] = aD; }
}

// -------------------------------------------- edge weights (no-max softmax)
// logits are O(+-6) by Glorot arithmetic -> exp cannot overflow; alpha ratio
// is identical without max subtraction.
template <int H>
__global__ __launch_bounds__(256) void k_escore(const int* __restrict__ csr_src,
                                                const int* __restrict__ csr_dst,
                                                const float* __restrict__ al_s,
                                                const float* __restrict__ al_d,
                                                float* __restrict__ w, int ET) {
    int i = blockIdx.x * 256 + threadIdx.x;
    if (i >= ET) return;
    int s = csr_src[i], d = csr_dst[i];
#pragma unroll
    for (int hh = 0; hh < H; ++hh) {
        float e = al_s[s * H + hh] + al_d[d * H + hh];
        e = e > 0.f ? e : NEG_SLOPE * e;
        w[i * H + hh] = __expf(e);
    }
}

// ---------------------------------------- gather-aggregate, 2 waves per node
// Wave accumulates sum(w_e * h[src_e]) over every-other edge into registers;
// LDS-combines with its partner wave; normalizes by 1/sum(w) at the end.
template <int H, int C, typename OutT>
__global__ __launch_bounds__(256) void k_aggw2(const _Float16* __restrict__ h,
                                               const float* __restrict__ w,
                                               const int* __restrict__ rowptr,
                                               const int* __restrict__ csr_src,
                                               const float* __restrict__ bias,
                                               OutT* __restrict__ out, int n) {
    constexpr int HC = H * C;
    constexpr int CA = HC / 96;    // 8 (HC=768) or 4 (HC=384)
    constexpr int CB = CA / 2;
    int wv = threadIdx.x >> 6;          // 0..3
    int lane = threadIdx.x & 63;
    int node = blockIdx.x * 2 + (wv >> 1);
    int half = wv & 1;
    int ns = wv >> 1;

    __shared__ float s_acc[2][64][CA + CB];
    __shared__ float s_sw[2][H];

    int beg = rowptr[node], end = rowptr[node + 1];

    float accA[CA] = {}, accB[CB] = {};
    float swsum[H] = {};

    for (int base = beg + half; base < end; base += 128) {
        int myi = base + 2 * lane;
        bool valid = myi < end;
        int sl = valid ? csr_src[myi] : 0;
        float wl[H];
#pragma unroll
        for (int hh = 0; hh < H; ++hh) {
            wl[hh] = valid ? w[myi * H + hh] : 0.f;
            swsum[hh] += wl[hh];
        }
        int cnt = min(64, (end - base + 1) >> 1);
        int j = 0;
        for (; j + 4 <= cnt; j += 4) {
            int ss0 = __shfl(sl, j + 0), ss1 = __shfl(sl, j + 1);
            int ss2 = __shfl(sl, j + 2), ss3 = __shfl(sl, j + 3);
            float wA0, wA1, wA2, wA3, wB0, wB1, wB2, wB3;
            if constexpr (H == 3) {
                float a0 = __shfl(wl[0], j + 0), b0 = __shfl(wl[1], j + 0), c0 = __shfl(wl[2], j + 0);
                float a1 = __shfl(wl[0], j + 1), b1 = __shfl(wl[1], j + 1), c1 = __shfl(wl[2], j + 1);
                float a2 = __shfl(wl[0], j + 2), b2 = __shfl(wl[1], j + 2), c2 = __shfl(wl[2], j + 2);
                float a3 = __shfl(wl[0], j + 3), b3 = __shfl(wl[1], j + 3), c3 = __shfl(wl[2], j + 3);
                wA0 = (lane < 32) ? a0 : b0; wB0 = c0;
                wA1 = (lane < 32) ? a1 : b1; wB1 = c1;
                wA2 = (lane < 32) ? a2 : b2; wB2 = c2;
                wA3 = (lane < 32) ? a3 : b3; wB3 = c3;
            } else {
                wA0 = wB0 = __shfl(wl[0], j + 0);
                wA1 = wB1 = __shfl(wl[0], j + 1);
                wA2 = wB2 = __shfl(wl[0], j + 2);
                wA3 = wB3 = __shfl(wl[0], j + 3);
            }
            const _Float16* r0 = h + (size_t)ss0 * HC;
            const _Float16* r1 = h + (size_t)ss1 * HC;
            const _Float16* r2 = h + (size_t)ss2 * HC;
            const _Float16* r3 = h + (size_t)ss3 * HC;
            if constexpr (CA == 8) {
                half8 va0 = *(const half8*)(r0 + lane * 8);
                half8 va1 = *(const half8*)(r1 + lane * 8);
                half8 va2 = *(const half8*)(r2 + lane * 8);
                half8 va3 = *(const half8*)(r3 + lane * 8);
                half4v vb0 = *(const half4v*)(r0 + 512 + lane * 4);
                half4v vb1 = *(const half4v*)(r1 + 512 + lane * 4);
                half4v vb2 = *(const half4v*)(r2 + 512 + lane * 4);
                half4v vb3 = *(const half4v*)(r3 + 512 + lane * 4);
#pragma unroll
                for (int k = 0; k < 8; ++k) {
                    accA[k] = fmaf(wA0, (float)va0[k], accA[k]);
                    accA[k] = fmaf(wA1, (float)va1[k], accA[k]);
                    accA[k] = fmaf(wA2, (float)va2[k], accA[k]);
                    accA[k] = fmaf(wA3, (float)va3[k], accA[k]);
                }
#pragma unroll
                for (int k = 0; k < 4; ++k) {
                    accB[k] = fmaf(wB0, (float)vb0[k], accB[k]);
                    accB[k] = fmaf(wB1, (float)vb1[k], accB[k]);
                    accB[k] = fmaf(wB2, (float)vb2[k], accB[k]);
                    accB[k] = fmaf(wB3, (float)vb3[k], accB[k]);
                }
            } else {
                half4v va0 = *(const half4v*)(r0 + lane * 4);
                half4v va1 = *(const half4v*)(r1 + lane * 4);
                half4v va2 = *(const half4v*)(r2 + lane * 4);
                half4v va3 = *(const half4v*)(r3 + lane * 4);
                half2v vb0 = *(const half2v*)(r0 + 256 + lane * 2);
                half2v vb1 = *(const half2v*)(r1 + 256 + lane * 2);
                half2v vb2 = *(const half2v*)(r2 + 256 + lane * 2);
                half2v vb3 = *(const half2v*)(r3 + 256 + lane * 2);
#pragma unroll
                for (int k = 0; k < 4; ++k) {
                    accA[k] = fmaf(wA0, (float)va0[k], accA[k]);
                    accA[k] = fmaf(wA1, (float)va1[k], accA[k]);
                    accA[k] = fmaf(wA2, (float)va2[k], accA[k]);
                    accA[k] = fmaf(wA3, (float)va3[k], accA[k]);
                }
#pragma unroll
                for (int k = 0; k < 2; ++k) {
                    accB[k] = fmaf(wB0, (float)vb0[k], accB[k]);
                    accB[k] = fmaf(wB1, (float)vb1[k], accB[k]);
                    accB[k] = fmaf(wB2, (float)vb2[k], accB[k]);
                    accB[k] = fmaf(wB3, (float)vb3[k], accB[k]);
                }
            }
        }
        for (; j < cnt; ++j) {
            int s = __shfl(sl, j);
            float aA, aB;
            if constexpr (H == 3) {
                float s0 = __shfl(wl[0], j);
                float s1 = __shfl(wl[1], j);
                float s2 = __shfl(wl[2], j);
                aA = (lane < 32) ? s0 : s1;
                aB = s2;
            } else {
                aA = aB = __shfl(wl[0], j);
            }
            const _Float16* row = h + (size_t)s * HC;
            if constexpr (CA == 8) {
                half8 va = *(const half8*)(row + lane * 8);
                half4v vb = *(const half4v*)(row + 512 + lane * 4);
#pragma unroll
                for (int k = 0; k < 8; ++k) accA[k] = fmaf(aA, (float)va[k], accA[k]);
#pragma unroll
                for (int k = 0; k < 4; ++k) accB[k] = fmaf(aB, (float)vb[k], accB[k]);
            } else {
                half4v va = *(const half4v*)(row + lane * 4);
                half2v vb = *(const half2v*)(row + 256 + lane * 2);
#pragma unroll
                for (int k = 0; k < 4; ++k) accA[k] = fmaf(aA, (float)va[k], accA[k]);
#pragma unroll
                for (int k = 0; k < 2; ++k) accB[k] = fmaf(aB, (float)vb[k], accB[k]);
            }
        }
    }

    // reduce weight sums across lanes (each lane held distinct edges)
#pragma unroll
    for (int hh = 0; hh < H; ++hh)
#pragma unroll
        for (int off = 32; off; off >>= 1) swsum[hh] += __shfl_xor(swsum[hh], off);

    // combine the two waves of this node
    if (half == 1) {
#pragma unroll
        for (int k = 0; k < CA; ++k) s_acc[ns][lane][k] = accA[k];
#pragma unroll
        for (int k = 0; k < CB; ++k) s_acc[ns][lane][CA + k] = accB[k];
        if (lane == 0) {
#pragma unroll
            for (int hh = 0; hh < H; ++hh) s_sw[ns][hh] = swsum[hh];
        }
    }
    __syncthreads();
    if (half == 1) return;

#pragma unroll
    for (int k = 0; k < CA; ++k) accA[k] += s_acc[ns][lane][k];
#pragma unroll
    for (int k = 0; k < CB; ++k) accB[k] += s_acc[ns][lane][CA + k];
    float inv[H];
#pragma unroll
    for (int hh = 0; hh < H; ++hh) inv[hh] = 1.f / (swsum[hh] + s_sw[ns][hh]);

    float invA = (H == 3) ? ((lane < 32) ? inv[0] : inv[H - 2]) : inv[0];
    float invB = inv[H - 1];

    size_t obase = (size_t)node * HC;
    int cA0 = lane * CA, cB0 = 64 * CA + lane * CB;
    if constexpr (sizeof(OutT) == 2) {
        _Float16* op = (_Float16*)out;
        if constexpr (CA == 8) {
            half8 oa;
#pragma unroll
            for (int k = 0; k < 8; ++k) {
                float v = accA[k] * invA + bias[cA0 + k];
                oa[k] = (_Float16)(v > 0.f ? v : 0.f);
            }
            *(half8*)(op + obase + cA0) = oa;
            half4v ob;
#pragma unroll
            for (int k = 0; k < 4; ++k) {
                float v = accB[k] * invB + bias[cB0 + k];
                ob[k] = (_Float16)(v > 0.f ? v : 0.f);
            }
            *(half4v*)(op + obase + cB0) = ob;
        } else {
            half4v oa;
#pragma unroll
            for (int k = 0; k < 4; ++k) {
                float v = accA[k] * invA + bias[cA0 + k];
                oa[k] = (_Float16)(v > 0.f ? v : 0.f);
            }
            *(half4v*)(op + obase + cA0) = oa;
            half2v ob;
#pragma unroll
            for (int k = 0; k < 2; ++k) {
                float v = accB[k] * invB + bias[cB0 + k];
                ob[k] = (_Float16)(v > 0.f ? v : 0.f);
            }
            *(half2v*)(op + obase + cB0) = ob;
        }
    } else {
        float* op = (float*)out;
        if constexpr (CA == 4) {
            float4 oa;
            float t0 = accA[0] * invA + bias[cA0 + 0]; oa.x = t0 > 0.f ? t0 : 0.f;
            float t1 = accA[1] * invA + bias[cA0 + 1]; oa.y = t1 > 0.f ? t1 : 0.f;
            float t2 = accA[2] * invA + bias[cA0 + 2]; oa.z = t2 > 0.f ? t2 : 0.f;
            float t3 = accA[3] * invA + bias[cA0 + 3]; oa.w = t3 > 0.f ? t3 : 0.f;
            *(float4*)(op + obase + cA0) = oa;
            floatx2 ob;
            float u0 = accB[0] * invB + bias[cB0 + 0]; ob[0] = u0 > 0.f ? u0 : 0.f;
            float u1 = accB[1] * invB + bias[cB0 + 1]; ob[1] = u1 > 0.f ? u1 : 0.f;
            *(floatx2*)(op + obase + cB0) = ob;
        } else {
#pragma unroll
            for (int k = 0; k < CA; ++k) {
                float v = accA[k] * invA + bias[cA0 + k];
                op[obase + cA0 + k] = v > 0.f ? v : 0.f;
            }
#pragma unroll
            for (int k = 0; k < CB; ++k) {
                float v = accB[k] * invB + bias[cB0 + k];
                op[obase + cB0 + k] = v > 0.f ? v : 0.f;
            }
        }
    }
}

// ---------------------------------------------------------------------- host
extern "C" void kernel_launch(void* const* d_in, const int* in_sizes, int n_in,
                              void* d_out, int out_size, void* d_ws, size_t ws_size,
                              hipStream_t stream) {
    const float* x   = (const float*)d_in[0];
    const int*   ei  = (const int*)d_in[1];
    const float* W1  = (const float*)d_in[2];
    const float* as1 = (const float*)d_in[3];
    const float* ad1 = (const float*)d_in[4];
    const float* b1  = (const float*)d_in[5];
    const float* W2  = (const float*)d_in[6];
    const float* as2 = (const float*)d_in[7];
    const float* ad2 = (const float*)d_in[8];
    const float* b2  = (const float*)d_in[9];
    float* out = (float*)d_out;

    const int N  = in_sizes[0] / 128;   // 20000
    const int E  = in_sizes[1] / 2;     // 320000
    const int ET = E + N;
    const int* src = ei;
    const int* dst = ei + E;

    char* ws = (char*)d_ws;
    size_t off = 0;
    auto alloc = [&](size_t bytes) {
        void* p = ws + off;
        off = (off + bytes + 255) & ~(size_t)255;
        return p;
    };
    _Float16* h1   = (_Float16*)alloc((size_t)N * 768 * 2);
    _Float16* h2   = (_Float16*)alloc((size_t)N * 384 * 2);
    _Float16* xh   = (_Float16*)alloc((size_t)N * 128 * 2);
    _Float16* x2h  = (_Float16*)alloc((size_t)N * 768 * 2);
    _Float16* w1t  = (_Float16*)alloc((size_t)768 * 128 * 2);
    _Float16* w2t  = (_Float16*)alloc((size_t)384 * 768 * 2);
    float* alS1 = (float*)alloc((size_t)N * 3 * 4);
    float* alD1 = (float*)alloc((size_t)N * 3 * 4);
    float* alS2 = (float*)alloc((size_t)N * 4);
    float* alD2 = (float*)alloc((size_t)N * 4);
    float* ew1  = (float*)alloc((size_t)ET * 3 * 4);
    float* ew2  = (float*)alloc((size_t)ET * 4);
    int* deg    = (int*)alloc((size_t)N * 4);
    int* rowptr = (int*)alloc((size_t)(N + 1) * 4);
    int* cursor = (int*)alloc((size_t)N * 4);
    int* csrs   = (int*)alloc((size_t)ET * 4);
    int* csrd   = (int*)alloc((size_t)ET * 4);

    // CSR by destination (shared by both layers)
    hipMemsetAsync(deg, 0, (size_t)N * 4, stream);
    k_hist<<<(ET + 255) / 256, 256, 0, stream>>>(dst, E, N, deg);
    k_scan<<<1, 256, 0, stream>>>(deg, rowptr, cursor, N);
    k_scatter<<<(ET + 255) / 256, 256, 0, stream>>>(src, dst, E, N, cursor, csrs, csrd);

    // operand prep (fp16)
    int n8 = N * 128 / 8;
    k_f2h8<<<(n8 + 255) / 256, 256, 0, stream>>>(x, xh, n8);
    k_transpose_h<<<(128 * 768 + 255) / 256, 256, 0, stream>>>(W1, w1t, 128, 768);
    k_transpose_h<<<(768 * 384 + 255) / 256, 256, 0, stream>>>(W2, w2t, 768, 384);

    // layer 1
    dim3 g1(768 / 128, (N + 127) / 128);
    k_hgemm<_Float16><<<g1, 256, 0, stream>>>(xh, w1t, h1, N, 768, 128);
    k_att<3, 256><<<(N * 3 + 3) / 4, 256, 0, stream>>>(h1, as1, ad1, alS1, alD1, N);
    k_escore<3><<<(ET + 255) / 256, 256, 0, stream>>>(csrs, csrd, alS1, alD1, ew1, ET);
    k_aggw2<3, 256, _Float16><<<N / 2, 256, 0, stream>>>(h1, ew1, rowptr, csrs, b1, x2h, N);

    // layer 2
    dim3 g2(384 / 128, (N + 127) / 128);
    k_hgemm<_Float16><<<g2, 256, 0, stream>>>(x2h, w2t, h2, N, 384, 768);
    k_att<1, 384><<<(N + 3) / 4, 256, 0, stream>>>(h2, as2, ad2, alS2, alD2, N);
    k_escore<1><<<(ET + 255) / 256, 256, 0, stream>>>(csrs, csrd, alS2, alD2, ew2, ET);
    k_aggw2<1, 384, float><<<N / 2, 256, 0, stream>>>(h2, ew2, rowptr, csrs, b2, out, N);
}

// Round 7
// 272.148 us; speedup vs baseline: 1.0318x; 1.0318x over previous
//
#include <hip/hip_runtime.h>
#include <hip/hip_bf16.h>

#define NEG_SLOPE 0.2f

typedef _Float16 half8 __attribute__((ext_vector_type(8)));
typedef _Float16 half4v __attribute__((ext_vector_type(4)));
typedef _Float16 half2v __attribute__((ext_vector_type(2)));
typedef float floatx4 __attribute__((ext_vector_type(4)));
typedef float floatx2 __attribute__((ext_vector_type(2)));

// ---------------------------------------------------------------- CSR build
__global__ void k_hist(const int* __restrict__ dst, int E, int n, int* __restrict__ deg) {
    int e = blockIdx.x * blockDim.x + threadIdx.x;
    int ET = E + n;
    if (e >= ET) return;
    int d = (e < E) ? dst[e] : (e - E);   // self-loops appended
    atomicAdd(&deg[d], 1);
}

__global__ void k_scan(const int* __restrict__ deg, int* __restrict__ rowptr,
                       int* __restrict__ cursor, int n) {
    __shared__ int part[256];
    int t = threadIdx.x;
    int chunk = (n + 255) / 256;
    int s0 = t * chunk, s1 = min(s0 + chunk, n);
    int s = 0;
    for (int i = s0; i < s1; ++i) s += deg[i];
    part[t] = s;
    __syncthreads();
    for (int off = 1; off < 256; off <<= 1) {
        int v = (t >= off) ? part[t - off] : 0;
        __syncthreads();
        part[t] += v;
        __syncthreads();
    }
    int run = (t == 0) ? 0 : part[t - 1];
    for (int i = s0; i < s1; ++i) { rowptr[i] = run; cursor[i] = run; run += deg[i]; }
    if (t == 255) rowptr[n] = run;
}

__global__ void k_scatter(const int* __restrict__ src, const int* __restrict__ dst,
                          int E, int n, int* __restrict__ cursor,
                          int* __restrict__ csr_src, int* __restrict__ csr_dst) {
    int e = blockIdx.x * blockDim.x + threadIdx.x;
    int ET = E + n;
    if (e >= ET) return;
    int s = (e < E) ? src[e] : (e - E);
    int d = (e < E) ? dst[e] : (e - E);
    int pos = atomicAdd(&cursor[d], 1);
    csr_src[pos] = s;
    csr_dst[pos] = d;
}

// ------------------------------------------------------------- conversions
__global__ void k_f2h8(const float* __restrict__ in, _Float16* __restrict__ out, int n8) {
    int i = blockIdx.x * 256 + threadIdx.x;
    if (i >= n8) return;
    const float4* p = (const float4*)in + (size_t)i * 2;
    float4 a = p[0], b = p[1];
    _Float16 h[8] = {(_Float16)a.x, (_Float16)a.y, (_Float16)a.z, (_Float16)a.w,
                     (_Float16)b.x, (_Float16)b.y, (_Float16)b.z, (_Float16)b.w};
    *(uint4*)(out + (size_t)i * 8) = *(const uint4*)h;
}

// W[R][C] fp32 -> Wt[C][R] fp16
__global__ void k_transpose_h(const float* __restrict__ W, _Float16* __restrict__ Wt,
                              int R, int C) {
    int i = blockIdx.x * 256 + threadIdx.x;
    if (i >= R * C) return;
    int c = i / R, r = i % R;
    Wt[i] = (_Float16)W[(size_t)r * C + c];
}

// ------------------------------------- attention projection vectors (tiny)
// vs1[h*128+k] = sum_c W1[k, h*256+c] * as1[h*256+c]   (and vd1 likewise)
__global__ void k_wv1(const float* __restrict__ W1, const float* __restrict__ as1,
                      const float* __restrict__ ad1, float* __restrict__ vs,
                      float* __restrict__ vd) {
    int t = blockIdx.x * blockDim.x + threadIdx.x;
    if (t >= 384) return;
    int h = t >> 7, k = t & 127;
    const float* wr = W1 + (size_t)k * 768 + h * 256;
    const float* ar = as1 + h * 256;
    const float* dr = ad1 + h * 256;
    float s = 0.f, d = 0.f;
    for (int c = 0; c < 256; ++c) { float wv = wr[c]; s += wv * ar[c]; d += wv * dr[c]; }
    vs[t] = s; vd[t] = d;
}

// vs2[k] = sum_c W2[k,c] * as2[c]
__global__ void k_wv2(const float* __restrict__ W2, const float* __restrict__ as2,
                      const float* __restrict__ ad2, float* __restrict__ vs,
                      float* __restrict__ vd) {
    int t = blockIdx.x * blockDim.x + threadIdx.x;
    if (t >= 768) return;
    const float* wr = W2 + (size_t)t * 384;
    float s = 0.f, d = 0.f;
    for (int c = 0; c < 384; ++c) { float wv = wr[c]; s += wv * as2[c]; d += wv * ad2[c]; }
    vs[t] = s; vd[t] = d;
}

// --------------------------------------------- layer-1 logits from x directly
__global__ __launch_bounds__(256) void k_attx1(const _Float16* __restrict__ xh,
        const float* __restrict__ vs, const float* __restrict__ vd,
        float* __restrict__ al_s, float* __restrict__ al_d, int n) {
    int wid = (blockIdx.x * blockDim.x + threadIdx.x) >> 6;
    int lane = threadIdx.x & 63;
    if (wid >= n) return;
    half2v xv = *(const half2v*)(xh + (size_t)wid * 128 + lane * 2);
    float f0 = (float)xv[0], f1 = (float)xv[1];
    float aS[3], aD[3];
#pragma unroll
    for (int hh = 0; hh < 3; ++hh) {
        floatx2 v = *(const floatx2*)(vs + hh * 128 + lane * 2);
        floatx2 d = *(const floatx2*)(vd + hh * 128 + lane * 2);
        aS[hh] = f0 * v[0] + f1 * v[1];
        aD[hh] = f0 * d[0] + f1 * d[1];
    }
#pragma unroll
    for (int hh = 0; hh < 3; ++hh)
#pragma unroll
        for (int off = 32; off; off >>= 1) {
            aS[hh] += __shfl_xor(aS[hh], off);
            aD[hh] += __shfl_xor(aD[hh], off);
        }
    if (lane == 0) {
#pragma unroll
        for (int hh = 0; hh < 3; ++hh) { al_s[wid * 3 + hh] = aS[hh]; al_d[wid * 3 + hh] = aD[hh]; }
    }
}

// --------------------------------------------- layer-2 logits from x2 directly
__global__ __launch_bounds__(256) void k_attx2(const _Float16* __restrict__ x2,
        const float* __restrict__ vs, const float* __restrict__ vd,
        float* __restrict__ al_s, float* __restrict__ al_d, int n) {
    int wid = (blockIdx.x * blockDim.x + threadIdx.x) >> 6;
    int lane = threadIdx.x & 63;
    if (wid >= n) return;
    const _Float16* xp = x2 + (size_t)wid * 768;
    half8 a = *(const half8*)(xp + lane * 8);
    half4v b = *(const half4v*)(xp + 512 + lane * 4);
    float aS = 0.f, aD = 0.f;
#pragma unroll
    for (int k = 0; k < 8; ++k) {
        float f = (float)a[k];
        aS += f * vs[lane * 8 + k];
        aD += f * vd[lane * 8 + k];
    }
#pragma unroll
    for (int k = 0; k < 4; ++k) {
        float f = (float)b[k];
        aS += f * vs[512 + lane * 4 + k];
        aD += f * vd[512 + lane * 4 + k];
    }
#pragma unroll
    for (int off = 32; off; off >>= 1) {
        aS += __shfl_xor(aS, off);
        aD += __shfl_xor(aD, off);
    }
    if (lane == 0) { al_s[wid] = aS; al_d[wid] = aD; }
}

// -------------------------------------------- edge weights (no-max softmax)
// logits are O(+-3) by Glorot arithmetic -> exp cannot overflow; alpha ratio
// is identical without max subtraction. (validated vs ref in R6, absmax 2e-3)
template <int H>
__global__ __launch_bounds__(256) void k_escore(const int* __restrict__ csr_src,
                                                const int* __restrict__ csr_dst,
                                                const float* __restrict__ al_s,
                                                const float* __restrict__ al_d,
                                                float* __restrict__ w, int ET) {
    int i = blockIdx.x * 256 + threadIdx.x;
    if (i >= ET) return;
    int s = csr_src[i], d = csr_dst[i];
#pragma unroll
    for (int hh = 0; hh < H; ++hh) {
        float e = al_s[s * H + hh] + al_d[d * H + hh];
        e = e > 0.f ? e : NEG_SLOPE * e;
        w[i * H + hh] = __expf(e);
    }
}

// ---------------------- layer-1 aggregation in INPUT space (x is 5MB, L2-fit)
// xagg[d,h,:] = (sum_e w[e,h] * x[src_e,:]) / sum_e w[e,h],  128 ch, fp16 out.
// One wave per node; 4 edge-slots x 16 chunk-lanes; one half8 covers a full
// x row per 16 lanes -> 4 edges per VMEM instruction.
__global__ __launch_bounds__(256) void k_aggx(const _Float16* __restrict__ xh,
                                              const float* __restrict__ w,
                                              const int* __restrict__ rowptr,
                                              const int* __restrict__ csr_src,
                                              _Float16* __restrict__ xagg,
                                              int n) {
    int wid = (blockIdx.x * blockDim.x + threadIdx.x) >> 6;
    int lane = threadIdx.x & 63;
    if (wid >= n) return;
    int beg = rowptr[wid], end = rowptr[wid + 1];
    int slot = lane >> 4;     // 0..3  (edge within group)
    int chunk = lane & 15;    // channel chunk: ch = chunk*8 .. +8

    float acc0[8] = {}, acc1[8] = {}, acc2[8] = {};
    float sw0 = 0.f, sw1 = 0.f, sw2 = 0.f;

    for (int base = beg; base < end; base += 4) {
        int e = base + slot;
        bool v = e < end;
        int s = v ? csr_src[e] : 0;
        float w0 = v ? w[e * 3 + 0] : 0.f;
        float w1 = v ? w[e * 3 + 1] : 0.f;
        float w2 = v ? w[e * 3 + 2] : 0.f;
        sw0 += w0; sw1 += w1; sw2 += w2;
        half8 xv = *(const half8*)(xh + (size_t)s * 128 + chunk * 8);
#pragma unroll
        for (int k = 0; k < 8; ++k) {
            float f = (float)xv[k];
            acc0[k] = fmaf(w0, f, acc0[k]);
            acc1[k] = fmaf(w1, f, acc1[k]);
            acc2[k] = fmaf(w2, f, acc2[k]);
        }
    }
    // combine the 4 edge-slots (chunk index preserved under xor 16/32)
#pragma unroll
    for (int k = 0; k < 8; ++k) {
        acc0[k] += __shfl_xor(acc0[k], 16); acc0[k] += __shfl_xor(acc0[k], 32);
        acc1[k] += __shfl_xor(acc1[k], 16); acc1[k] += __shfl_xor(acc1[k], 32);
        acc2[k] += __shfl_xor(acc2[k], 16); acc2[k] += __shfl_xor(acc2[k], 32);
    }
    sw0 += __shfl_xor(sw0, 16); sw0 += __shfl_xor(sw0, 32);
    sw1 += __shfl_xor(sw1, 16); sw1 += __shfl_xor(sw1, 32);
    sw2 += __shfl_xor(sw2, 16); sw2 += __shfl_xor(sw2, 32);

    if (lane < 16) {
        float i0 = 1.f / sw0, i1 = 1.f / sw1, i2 = 1.f / sw2;
        _Float16* op = xagg + (size_t)wid * 384 + chunk * 8;
        half8 o0, o1, o2;
#pragma unroll
        for (int k = 0; k < 8; ++k) {
            o0[k] = (_Float16)(acc0[k] * i0);
            o1[k] = (_Float16)(acc1[k] * i1);
            o2[k] = (_Float16)(acc2[k] * i2);
        }
        *(half8*)(op + 0)   = o0;
        *(half8*)(op + 128) = o1;
        *(half8*)(op + 256) = o2;
    }
}

// ------------------------------------------------------------ fp16 MFMA GEMM
// GAT=false: C = A[M,K] @ Bt[N,K]^T (raw).
// GAT=true : A is xagg[M][3][128], head chosen by output col block (col/256),
//            K=128, epilogue adds bias + ReLU.
__device__ __forceinline__ void gload_lds16(const _Float16* g, _Float16* l) {
    __builtin_amdgcn_global_load_lds((const __attribute__((address_space(1))) void*)g,
                                     (__attribute__((address_space(3))) void*)l,
                                     16, 0, 0);
}

template <typename OutT, bool GAT>
__global__ __launch_bounds__(256) void k_hgemm(const _Float16* __restrict__ A,
                                               const _Float16* __restrict__ Bt,
                                               const float* __restrict__ bias,
                                               OutT* __restrict__ C,
                                               int M, int N, int K) {
    __shared__ _Float16 lds[2 * 8192];       // [buf][A:4096|B:4096] elems (32KB)
    int t = threadIdx.x;
    int lane = t & 63, w = t >> 6;
    int wr = w >> 1, wc = w & 1;
    int lrow = lane & 15, lko = lane >> 4;
    int row0 = blockIdx.y * 128, col0 = blockIdx.x * 128;

    int sr = t & 127;
    int sko = t >> 7;
    int agr = row0 + sr; if (agr >= M) agr = M - 1;
    const _Float16* aRow;
    if constexpr (GAT) {
        int head = col0 >> 8;                    // col block -> head (256 cols/head)
        aRow = A + (size_t)agr * 384 + head * 128;
    } else {
        aRow = A + (size_t)agr * K;
    }
    const _Float16* bRow = Bt + (size_t)(col0 + sr) * K;

    floatx4 acc[4][4] = {};

    int nk = K >> 5;
#pragma unroll
    for (int s = 0; s < 2; ++s) {
        int ko = s * 2 + sko;
        gload_lds16(aRow + ko * 8, lds + s * 2048 + t * 8);
        gload_lds16(bRow + ko * 8, lds + 4096 + s * 2048 + t * 8);
    }
    __syncthreads();

    for (int ks = 0; ks < nk; ++ks) {
        int buf = ks & 1;
        if (ks + 1 < nk) {
            int kt = (ks + 1) << 5;
            _Float16* dstb = lds + (buf ^ 1) * 8192;
#pragma unroll
            for (int s = 0; s < 2; ++s) {
                int ko = s * 2 + sko;
                gload_lds16(aRow + kt + ko * 8, dstb + s * 2048 + t * 8);
                gload_lds16(bRow + kt + ko * 8, dstb + 4096 + s * 2048 + t * 8);
            }
        }
        const _Float16* base = lds + buf * 8192 + lko * 1024;
        half8 af[4], bf[4];
#pragma unroll
        for (int mi = 0; mi < 4; ++mi)
            af[mi] = *(const half8*)(base + (wr * 64 + mi * 16 + lrow) * 8);
#pragma unroll
        for (int ni = 0; ni < 4; ++ni)
            bf[ni] = *(const half8*)(base + 4096 + (wc * 64 + ni * 16 + lrow) * 8);
#pragma unroll
        for (int mi = 0; mi < 4; ++mi)
#pragma unroll
            for (int ni = 0; ni < 4; ++ni)
                acc[mi][ni] = __builtin_amdgcn_mfma_f32_16x16x32_f16(
                    af[mi], bf[ni], acc[mi][ni], 0, 0, 0);
        __syncthreads();
    }

#pragma unroll
    for (int mi = 0; mi < 4; ++mi) {
        int rb = row0 + wr * 64 + mi * 16 + lko * 4;
#pragma unroll
        for (int ni = 0; ni < 4; ++ni) {
            int col = col0 + wc * 64 + ni * 16 + lrow;
#pragma unroll
            for (int j = 0; j < 4; ++j) {
                int row = rb + j;
                if (row < M) {
                    float v = acc[mi][ni][j];
                    if constexpr (GAT) { v += bias[col]; v = v > 0.f ? v : 0.f; }
                    C[(size_t)row * N + col] = (OutT)v;
                }
            }
        }
    }
}

// ---------------------------------------- layer-2 gather-agg, 2 waves per node
template <int H, int C, typename OutT>
__global__ __launch_bounds__(256) void k_aggw2(const _Float16* __restrict__ h,
                                               const float* __restrict__ w,
                                               const int* __restrict__ rowptr,
                                               const int* __restrict__ csr_src,
                                               const float* __restrict__ bias,
                                               OutT* __restrict__ out, int n) {
    constexpr int HC = H * C;
    constexpr int CA = HC / 96;    // 4 for HC=384
    constexpr int CB = CA / 2;
    int wv = threadIdx.x >> 6;
    int lane = threadIdx.x & 63;
    int node = blockIdx.x * 2 + (wv >> 1);
    int half = wv & 1;
    int ns = wv >> 1;

    __shared__ float s_acc[2][64][CA + CB];
    __shared__ float s_sw[2][H];

    int beg = rowptr[node], end = rowptr[node + 1];

    float accA[CA] = {}, accB[CB] = {};
    float swsum[H] = {};

    for (int base = beg + half; base < end; base += 128) {
        int myi = base + 2 * lane;
        bool valid = myi < end;
        int sl = valid ? csr_src[myi] : 0;
        float wl[H];
#pragma unroll
        for (int hh = 0; hh < H; ++hh) {
            wl[hh] = valid ? w[myi * H + hh] : 0.f;
            swsum[hh] += wl[hh];
        }
        int cnt = min(64, (end - base + 1) >> 1);
        int j = 0;
        for (; j + 4 <= cnt; j += 4) {
            int ss0 = __shfl(sl, j + 0), ss1 = __shfl(sl, j + 1);
            int ss2 = __shfl(sl, j + 2), ss3 = __shfl(sl, j + 3);
            float wA0 = __shfl(wl[0], j + 0), wA1 = __shfl(wl[0], j + 1);
            float wA2 = __shfl(wl[0], j + 2), wA3 = __shfl(wl[0], j + 3);
            const _Float16* r0 = h + (size_t)ss0 * HC;
            const _Float16* r1 = h + (size_t)ss1 * HC;
            const _Float16* r2 = h + (size_t)ss2 * HC;
            const _Float16* r3 = h + (size_t)ss3 * HC;
            half4v va0 = *(const half4v*)(r0 + lane * 4);
            half4v va1 = *(const half4v*)(r1 + lane * 4);
            half4v va2 = *(const half4v*)(r2 + lane * 4);
            half4v va3 = *(const half4v*)(r3 + lane * 4);
            half2v vb0 = *(const half2v*)(r0 + 256 + lane * 2);
            half2v vb1 = *(const half2v*)(r1 + 256 + lane * 2);
            half2v vb2 = *(const half2v*)(r2 + 256 + lane * 2);
            half2v vb3 = *(const half2v*)(r3 + 256 + lane * 2);
#pragma unroll
            for (int k = 0; k < 4; ++k) {
                accA[k] = fmaf(wA0, (float)va0[k], accA[k]);
                accA[k] = fmaf(wA1, (float)va1[k], accA[k]);
                accA[k] = fmaf(wA2, (float)va2[k], accA[k]);
                accA[k] = fmaf(wA3, (float)va3[k], accA[k]);
            }
#pragma unroll
            for (int k = 0; k < 2; ++k) {
                accB[k] = fmaf(wA0, (float)vb0[k], accB[k]);
                accB[k] = fmaf(wA1, (float)vb1[k], accB[k]);
                accB[k] = fmaf(wA2, (float)vb2[k], accB[k]);
                accB[k] = fmaf(wA3, (float)vb3[k], accB[k]);
            }
        }
        for (; j < cnt; ++j) {
            int s = __shfl(sl, j);
            float aA = __shfl(wl[0], j);
            const _Float16* row = h + (size_t)s * HC;
            half4v va = *(const half4v*)(row + lane * 4);
            half2v vb = *(const half2v*)(row + 256 + lane * 2);
#pragma unroll
            for (int k = 0; k < 4; ++k) accA[k] = fmaf(aA, (float)va[k], accA[k]);
#pragma unroll
            for (int k = 0; k < 2; ++k) accB[k] = fmaf(aA, (float)vb[k], accB[k]);
        }
    }

#pragma unroll
    for (int hh = 0; hh < H; ++hh)
#pragma unroll
        for (int off = 32; off; off >>= 1) swsum[hh] += __shfl_xor(swsum[hh], off);

    if (half == 1) {
#pragma unroll
        for (int k = 0; k < CA; ++k) s_acc[ns][lane][k] = accA[k];
#pragma unroll
        for (int k = 0; k < CB; ++k) s_acc[ns][lane][CA + k] = accB[k];
        if (lane == 0) {
#pragma unroll
            for (int hh = 0; hh < H; ++hh) s_sw[ns][hh] = swsum[hh];
        }
    }
    __syncthreads();
    if (half == 1) return;

#pragma unroll
    for (int k = 0; k < CA; ++k) accA[k] += s_acc[ns][lane][k];
#pragma unroll
    for (int k = 0; k < CB; ++k) accB[k] += s_acc[ns][lane][CA + k];
    float inv = 1.f / (swsum[0] + s_sw[ns][0]);

    size_t obase = (size_t)node * HC;
    int cA0 = lane * CA, cB0 = 64 * CA + lane * CB;
    float* op = (float*)out;
    float4 oa;
    float t0 = accA[0] * inv + bias[cA0 + 0]; oa.x = t0 > 0.f ? t0 : 0.f;
    float t1 = accA[1] * inv + bias[cA0 + 1]; oa.y = t1 > 0.f ? t1 : 0.f;
    float t2 = accA[2] * inv + bias[cA0 + 2]; oa.z = t2 > 0.f ? t2 : 0.f;
    float t3 = accA[3] * inv + bias[cA0 + 3]; oa.w = t3 > 0.f ? t3 : 0.f;
    *(float4*)(op + obase + cA0) = oa;
    floatx2 ob;
    float u0 = accB[0] * inv + bias[cB0 + 0]; ob[0] = u0 > 0.f ? u0 : 0.f;
    float u1 = accB[1] * inv + bias[cB0 + 1]; ob[1] = u1 > 0.f ? u1 : 0.f;
    *(floatx2*)(op + obase + cB0) = ob;
}

// ---------------------------------------------------------------------- host
extern "C" void kernel_launch(void* const* d_in, const int* in_sizes, int n_in,
                              void* d_out, int out_size, void* d_ws, size_t ws_size,
                              hipStream_t stream) {
    const float* x   = (const float*)d_in[0];
    const int*   ei  = (const int*)d_in[1];
    const float* W1  = (const float*)d_in[2];
    const float* as1 = (const float*)d_in[3];
    const float* ad1 = (const float*)d_in[4];
    const float* b1  = (const float*)d_in[5];
    const float* W2  = (const float*)d_in[6];
    const float* as2 = (const float*)d_in[7];
    const float* ad2 = (const float*)d_in[8];
    const float* b2  = (const float*)d_in[9];
    float* out = (float*)d_out;

    const int N  = in_sizes[0] / 128;   // 20000
    const int E  = in_sizes[1] / 2;     // 320000
    const int ET = E + N;
    const int* src = ei;
    const int* dst = ei + E;

    char* ws = (char*)d_ws;
    size_t off = 0;
    auto alloc = [&](size_t bytes) {
        void* p = ws + off;
        off = (off + bytes + 255) & ~(size_t)255;
        return p;
    };
    _Float16* xh    = (_Float16*)alloc((size_t)N * 128 * 2);
    _Float16* xagg  = (_Float16*)alloc((size_t)N * 384 * 2);
    _Float16* x2h   = (_Float16*)alloc((size_t)N * 768 * 2);
    _Float16* h2    = (_Float16*)alloc((size_t)N * 384 * 2);
    _Float16* w1t   = (_Float16*)alloc((size_t)768 * 128 * 2);
    _Float16* w2t   = (_Float16*)alloc((size_t)384 * 768 * 2);
    float* vs1  = (float*)alloc(384 * 4);
    float* vd1  = (float*)alloc(384 * 4);
    float* vs2  = (float*)alloc(768 * 4);
    float* vd2  = (float*)alloc(768 * 4);
    float* alS1 = (float*)alloc((size_t)N * 3 * 4);
    float* alD1 = (float*)alloc((size_t)N * 3 * 4);
    float* alS2 = (float*)alloc((size_t)N * 4);
    float* alD2 = (float*)alloc((size_t)N * 4);
    float* ew1  = (float*)alloc((size_t)ET * 3 * 4);
    float* ew2  = (float*)alloc((size_t)ET * 4);
    int* deg    = (int*)alloc((size_t)N * 4);
    int* rowptr = (int*)alloc((size_t)(N + 1) * 4);
    int* cursor = (int*)alloc((size_t)N * 4);
    int* csrs   = (int*)alloc((size_t)ET * 4);
    int* csrd   = (int*)alloc((size_t)ET * 4);

    // CSR by destination (shared by both layers)
    hipMemsetAsync(deg, 0, (size_t)N * 4, stream);
    k_hist<<<(ET + 255) / 256, 256, 0, stream>>>(dst, E, N, deg);
    k_scan<<<1, 256, 0, stream>>>(deg, rowptr, cursor, N);
    k_scatter<<<(ET + 255) / 256, 256, 0, stream>>>(src, dst, E, N, cursor, csrs, csrd);

    // operand prep
    int n8 = N * 128 / 8;
    k_f2h8<<<(n8 + 255) / 256, 256, 0, stream>>>(x, xh, n8);
    k_transpose_h<<<(128 * 768 + 255) / 256, 256, 0, stream>>>(W1, w1t, 128, 768);
    k_transpose_h<<<(768 * 384 + 255) / 256, 256, 0, stream>>>(W2, w2t, 768, 384);
    k_wv1<<<2, 256, 0, stream>>>(W1, as1, ad1, vs1, vd1);
    k_wv2<<<3, 256, 0, stream>>>(W2, as2, ad2, vs2, vd2);

    // layer 1: logits from x, aggregate in input space, then GEMM+bias+relu
    k_attx1<<<(N + 3) / 4, 256, 0, stream>>>(xh, vs1, vd1, alS1, alD1, N);
    k_escore<3><<<(ET + 255) / 256, 256, 0, stream>>>(csrs, csrd, alS1, alD1, ew1, ET);
    k_aggx<<<(N + 3) / 4, 256, 0, stream>>>(xh, ew1, rowptr, csrs, xagg, N);
    dim3 g1(768 / 128, (N + 127) / 128);
    k_hgemm<_Float16, true><<<g1, 256, 0, stream>>>(xagg, w1t, b1, x2h, N, 768, 128);

    // layer 2
    k_attx2<<<(N + 3) / 4, 256, 0, stream>>>(x2h, vs2, vd2, alS2, alD2, N);
    k_escore<1><<<(ET + 255) / 256, 256, 0, stream>>>(csrs, csrd, alS2, alD2, ew2, ET);
    dim3 g2(384 / 128, (N + 127) / 128);
    k_hgemm<_Float16, false><<<g2, 256, 0, stream>>>(x2h, w2t, nullptr, h2, N, 384, 768);
    k_aggw2<1, 384, float><<<N / 2, 256, 0, stream>>>(h2, ew2, rowptr, csrs, b2, out, N);
}

// Round 8
// 229.450 us; speedup vs baseline: 1.2238x; 1.1861x over previous
//
#include <hip/hip_runtime.h>
#include <hip/hip_bf16.h>

#define NEG_SLOPE 0.2f

typedef _Float16 half8 __attribute__((ext_vector_type(8)));
typedef _Float16 half4v __attribute__((ext_vector_type(4)));
typedef _Float16 half2v __attribute__((ext_vector_type(2)));
typedef float floatx4 __attribute__((ext_vector_type(4)));
typedef float floatx2 __attribute__((ext_vector_type(2)));

// ---------------------------------------------------------------- CSR build
__global__ void k_hist(const int* __restrict__ dst, int E, int n, int* __restrict__ deg) {
    int e = blockIdx.x * blockDim.x + threadIdx.x;
    int ET = E + n;
    if (e >= ET) return;
    int d = (e < E) ? dst[e] : (e - E);   // self-loops appended
    atomicAdd(&deg[d], 1);
}

// multi-block scan, phase 1: per-block sums (coalesced)
__global__ void k_scan1(const int* __restrict__ deg, int* __restrict__ bsum, int n) {
    __shared__ int red[256];
    int t = threadIdx.x, b = blockIdx.x;
    int i = b * 256 + t;
    red[t] = (i < n) ? deg[i] : 0;
    __syncthreads();
    for (int off = 128; off; off >>= 1) {
        if (t < off) red[t] += red[t + off];
        __syncthreads();
    }
    if (t == 0) bsum[b] = red[0];
}

// phase 2: exclusive scan of block sums (1 block, nb <= 256)
__global__ void k_scan2(const int* __restrict__ bsum, int* __restrict__ boff, int nb) {
    __shared__ int s[256];
    int t = threadIdx.x;
    s[t] = (t < nb) ? bsum[t] : 0;
    __syncthreads();
    for (int off = 1; off < 256; off <<= 1) {
        int v = (t >= off) ? s[t - off] : 0;
        __syncthreads();
        s[t] += v;
        __syncthreads();
    }
    if (t < nb) boff[t] = (t == 0) ? 0 : s[t - 1];
}

// phase 3: block-local inclusive scan + block offset -> rowptr/cursor
__global__ void k_scan3(const int* __restrict__ deg, const int* __restrict__ boff,
                        int* __restrict__ rowptr, int* __restrict__ cursor, int n) {
    __shared__ int s[256];
    int t = threadIdx.x, b = blockIdx.x;
    int i = b * 256 + t;
    int v = (i < n) ? deg[i] : 0;
    s[t] = v;
    __syncthreads();
    for (int off = 1; off < 256; off <<= 1) {
        int u = (t >= off) ? s[t - off] : 0;
        __syncthreads();
        s[t] += u;
        __syncthreads();
    }
    int incl = s[t];
    int base = boff[b];
    if (i < n) {
        rowptr[i] = base + incl - v;
        cursor[i] = base + incl - v;
        if (i == n - 1) rowptr[n] = base + incl;
    }
}

__global__ void k_scatter(const int* __restrict__ src, const int* __restrict__ dst,
                          int E, int n, int* __restrict__ cursor,
                          int* __restrict__ csr_src) {
    int e = blockIdx.x * blockDim.x + threadIdx.x;
    int ET = E + n;
    if (e >= ET) return;
    int s = (e < E) ? src[e] : (e - E);
    int d = (e < E) ? dst[e] : (e - E);
    int pos = atomicAdd(&cursor[d], 1);
    csr_src[pos] = s;
}

// ------------------------------------------------------------- conversions
// W[R][C] fp32 -> Wt[C][R] fp16
__global__ void k_transpose_h(const float* __restrict__ W, _Float16* __restrict__ Wt,
                              int R, int C) {
    int i = blockIdx.x * 256 + threadIdx.x;
    if (i >= R * C) return;
    int c = i / R, r = i % R;
    Wt[i] = (_Float16)W[(size_t)r * C + c];
}

// ------------------------------------- attention projection vectors (tiny)
__global__ void k_wv1(const float* __restrict__ W1, const float* __restrict__ as1,
                      const float* __restrict__ ad1, float* __restrict__ vs,
                      float* __restrict__ vd) {
    int t = blockIdx.x * blockDim.x + threadIdx.x;
    if (t >= 384) return;
    int h = t >> 7, k = t & 127;
    const float* wr = W1 + (size_t)k * 768 + h * 256;
    const float* ar = as1 + h * 256;
    const float* dr = ad1 + h * 256;
    float s = 0.f, d = 0.f;
    for (int c = 0; c < 256; ++c) { float wv = wr[c]; s += wv * ar[c]; d += wv * dr[c]; }
    vs[t] = s; vd[t] = d;
}

__global__ void k_wv2(const float* __restrict__ W2, const float* __restrict__ as2,
                      const float* __restrict__ ad2, float* __restrict__ vs,
                      float* __restrict__ vd) {
    int t = blockIdx.x * blockDim.x + threadIdx.x;
    if (t >= 768) return;
    const float* wr = W2 + (size_t)t * 384;
    float s = 0.f, d = 0.f;
    for (int c = 0; c < 384; ++c) { float wv = wr[c]; s += wv * as2[c]; d += wv * ad2[c]; }
    vs[t] = s; vd[t] = d;
}

// -------------------------- fused x fp32->fp16 + layer-1 logits (one pass)
__global__ __launch_bounds__(256) void k_prep1(const float* __restrict__ x,
        _Float16* __restrict__ xh, const float* __restrict__ vs,
        const float* __restrict__ vd, float* __restrict__ al_s,
        float* __restrict__ al_d, int n) {
    int wid = (blockIdx.x * blockDim.x + threadIdx.x) >> 6;
    int lane = threadIdx.x & 63;
    if (wid >= n) return;
    float2 f = *(const float2*)(x + (size_t)wid * 128 + lane * 2);
    half2v hv; hv[0] = (_Float16)f.x; hv[1] = (_Float16)f.y;
    *(half2v*)(xh + (size_t)wid * 128 + lane * 2) = hv;
    float aS[3], aD[3];
#pragma unroll
    for (int hh = 0; hh < 3; ++hh) {
        floatx2 v = *(const floatx2*)(vs + hh * 128 + lane * 2);
        floatx2 d = *(const floatx2*)(vd + hh * 128 + lane * 2);
        aS[hh] = f.x * v[0] + f.y * v[1];
        aD[hh] = f.x * d[0] + f.y * d[1];
    }
#pragma unroll
    for (int hh = 0; hh < 3; ++hh)
#pragma unroll
        for (int off = 32; off; off >>= 1) {
            aS[hh] += __shfl_xor(aS[hh], off);
            aD[hh] += __shfl_xor(aD[hh], off);
        }
    if (lane == 0) {
#pragma unroll
        for (int hh = 0; hh < 3; ++hh) { al_s[wid * 3 + hh] = aS[hh]; al_d[wid * 3 + hh] = aD[hh]; }
    }
}

// --------------------------------------------- layer-2 logits from x2 directly
__global__ __launch_bounds__(256) void k_attx2(const _Float16* __restrict__ x2,
        const float* __restrict__ vs, const float* __restrict__ vd,
        float* __restrict__ al_s, float* __restrict__ al_d, int n) {
    int wid = (blockIdx.x * blockDim.x + threadIdx.x) >> 6;
    int lane = threadIdx.x & 63;
    if (wid >= n) return;
    const _Float16* xp = x2 + (size_t)wid * 768;
    half8 a = *(const half8*)(xp + lane * 8);
    half4v b = *(const half4v*)(xp + 512 + lane * 4);
    float aS = 0.f, aD = 0.f;
#pragma unroll
    for (int k = 0; k < 8; ++k) {
        float f = (float)a[k];
        aS += f * vs[lane * 8 + k];
        aD += f * vd[lane * 8 + k];
    }
#pragma unroll
    for (int k = 0; k < 4; ++k) {
        float f = (float)b[k];
        aS += f * vs[512 + lane * 4 + k];
        aD += f * vd[512 + lane * 4 + k];
    }
#pragma unroll
    for (int off = 32; off; off >>= 1) {
        aS += __shfl_xor(aS, off);
        aD += __shfl_xor(aD, off);
    }
    if (lane == 0) { al_s[wid] = aS; al_d[wid] = aD; }
}

// ---------------------- layer-1 aggregation in INPUT space, inline edge exp
// No-max softmax: logits are O(+-3) by Glorot arithmetic -> exp safe; alpha
// ratio identical (validated R6/R7, absmax 2e-3).
__global__ __launch_bounds__(256) void k_aggx(const _Float16* __restrict__ xh,
                                              const float* __restrict__ al_s,
                                              const float* __restrict__ al_d,
                                              const int* __restrict__ rowptr,
                                              const int* __restrict__ csr_src,
                                              _Float16* __restrict__ xagg,
                                              int n) {
    int wid = (blockIdx.x * blockDim.x + threadIdx.x) >> 6;
    int lane = threadIdx.x & 63;
    if (wid >= n) return;
    int beg = rowptr[wid], end = rowptr[wid + 1];
    int slot = lane >> 4;     // 0..3  (edge within group)
    int chunk = lane & 15;    // channel chunk: ch = chunk*8 .. +8

    float ald0 = al_d[wid * 3 + 0], ald1 = al_d[wid * 3 + 1], ald2 = al_d[wid * 3 + 2];

    float acc0[8] = {}, acc1[8] = {}, acc2[8] = {};
    float sw0 = 0.f, sw1 = 0.f, sw2 = 0.f;

    for (int base = beg; base < end; base += 4) {
        int e = base + slot;
        bool v = e < end;
        int s = v ? csr_src[e] : 0;
        float w0 = 0.f, w1 = 0.f, w2 = 0.f;
        if (v) {
            float e0 = al_s[s * 3 + 0] + ald0; e0 = e0 > 0.f ? e0 : NEG_SLOPE * e0;
            float e1 = al_s[s * 3 + 1] + ald1; e1 = e1 > 0.f ? e1 : NEG_SLOPE * e1;
            float e2 = al_s[s * 3 + 2] + ald2; e2 = e2 > 0.f ? e2 : NEG_SLOPE * e2;
            w0 = __expf(e0); w1 = __expf(e1); w2 = __expf(e2);
        }
        sw0 += w0; sw1 += w1; sw2 += w2;
        half8 xv = *(const half8*)(xh + (size_t)s * 128 + chunk * 8);
#pragma unroll
        for (int k = 0; k < 8; ++k) {
            float f = (float)xv[k];
            acc0[k] = fmaf(w0, f, acc0[k]);
            acc1[k] = fmaf(w1, f, acc1[k]);
            acc2[k] = fmaf(w2, f, acc2[k]);
        }
    }
    // combine the 4 edge-slots (chunk index preserved under xor 16/32)
#pragma unroll
    for (int k = 0; k < 8; ++k) {
        acc0[k] += __shfl_xor(acc0[k], 16); acc0[k] += __shfl_xor(acc0[k], 32);
        acc1[k] += __shfl_xor(acc1[k], 16); acc1[k] += __shfl_xor(acc1[k], 32);
        acc2[k] += __shfl_xor(acc2[k], 16); acc2[k] += __shfl_xor(acc2[k], 32);
    }
    sw0 += __shfl_xor(sw0, 16); sw0 += __shfl_xor(sw0, 32);
    sw1 += __shfl_xor(sw1, 16); sw1 += __shfl_xor(sw1, 32);
    sw2 += __shfl_xor(sw2, 16); sw2 += __shfl_xor(sw2, 32);

    if (lane < 16) {
        float i0 = 1.f / sw0, i1 = 1.f / sw1, i2 = 1.f / sw2;
        _Float16* op = xagg + (size_t)wid * 384 + chunk * 8;
        half8 o0, o1, o2;
#pragma unroll
        for (int k = 0; k < 8; ++k) {
            o0[k] = (_Float16)(acc0[k] * i0);
            o1[k] = (_Float16)(acc1[k] * i1);
            o2[k] = (_Float16)(acc2[k] * i2);
        }
        *(half8*)(op + 0)   = o0;
        *(half8*)(op + 128) = o1;
        *(half8*)(op + 256) = o2;
    }
}

// ------------------------------------------------------------ fp16 MFMA GEMM
__device__ __forceinline__ void gload_lds16(const _Float16* g, _Float16* l) {
    __builtin_amdgcn_global_load_lds((const __attribute__((address_space(1))) void*)g,
                                     (__attribute__((address_space(3))) void*)l,
                                     16, 0, 0);
}

template <typename OutT, bool GAT>
__global__ __launch_bounds__(256) void k_hgemm(const _Float16* __restrict__ A,
                                               const _Float16* __restrict__ Bt,
                                               const float* __restrict__ bias,
                                               OutT* __restrict__ C,
                                               int M, int N, int K) {
    __shared__ _Float16 lds[2 * 8192];       // [buf][A:4096|B:4096] elems (32KB)
    int t = threadIdx.x;
    int lane = t & 63, w = t >> 6;
    int wr = w >> 1, wc = w & 1;
    int lrow = lane & 15, lko = lane >> 4;
    int row0 = blockIdx.y * 128, col0 = blockIdx.x * 128;

    int sr = t & 127;
    int sko = t >> 7;
    int agr = row0 + sr; if (agr >= M) agr = M - 1;
    const _Float16* aRow;
    if constexpr (GAT) {
        int head = col0 >> 8;                    // col block -> head (256 cols/head)
        aRow = A + (size_t)agr * 384 + head * 128;
    } else {
        aRow = A + (size_t)agr * K;
    }
    const _Float16* bRow = Bt + (size_t)(col0 + sr) * K;

    floatx4 acc[4][4] = {};

    int nk = K >> 5;
#pragma unroll
    for (int s = 0; s < 2; ++s) {
        int ko = s * 2 + sko;
        gload_lds16(aRow + ko * 8, lds + s * 2048 + t * 8);
        gload_lds16(bRow + ko * 8, lds + 4096 + s * 2048 + t * 8);
    }
    __syncthreads();

    for (int ks = 0; ks < nk; ++ks) {
        int buf = ks & 1;
        if (ks + 1 < nk) {
            int kt = (ks + 1) << 5;
            _Float16* dstb = lds + (buf ^ 1) * 8192;
#pragma unroll
            for (int s = 0; s < 2; ++s) {
                int ko = s * 2 + sko;
                gload_lds16(aRow + kt + ko * 8, dstb + s * 2048 + t * 8);
                gload_lds16(bRow + kt + ko * 8, dstb + 4096 + s * 2048 + t * 8);
            }
        }
        const _Float16* base = lds + buf * 8192 + lko * 1024;
        half8 af[4], bf[4];
#pragma unroll
        for (int mi = 0; mi < 4; ++mi)
            af[mi] = *(const half8*)(base + (wr * 64 + mi * 16 + lrow) * 8);
#pragma unroll
        for (int ni = 0; ni < 4; ++ni)
            bf[ni] = *(const half8*)(base + 4096 + (wc * 64 + ni * 16 + lrow) * 8);
#pragma unroll
        for (int mi = 0; mi < 4; ++mi)
#pragma unroll
            for (int ni = 0; ni < 4; ++ni)
                acc[mi][ni] = __builtin_amdgcn_mfma_f32_16x16x32_f16(
                    af[mi], bf[ni], acc[mi][ni], 0, 0, 0);
        __syncthreads();
    }

#pragma unroll
    for (int mi = 0; mi < 4; ++mi) {
        int rb = row0 + wr * 64 + mi * 16 + lko * 4;
#pragma unroll
        for (int ni = 0; ni < 4; ++ni) {
            int col = col0 + wc * 64 + ni * 16 + lrow;
#pragma unroll
            for (int j = 0; j < 4; ++j) {
                int row = rb + j;
                if (row < M) {
                    float v = acc[mi][ni][j];
                    if constexpr (GAT) { v += bias[col]; v = v > 0.f ? v : 0.f; }
                    C[(size_t)row * N + col] = (OutT)v;
                }
            }
        }
    }
}

// -------------------- layer-2 gather-agg, 2 waves per node, inline edge exp
__global__ __launch_bounds__(256) void k_aggw2(const _Float16* __restrict__ h,
                                               const float* __restrict__ al_s,
                                               const float* __restrict__ al_d,
                                               const int* __restrict__ rowptr,
                                               const int* __restrict__ csr_src,
                                               const float* __restrict__ bias,
                                               float* __restrict__ out, int n) {
    constexpr int HC = 384;
    constexpr int CA = 4;
    constexpr int CB = 2;
    int wv = threadIdx.x >> 6;
    int lane = threadIdx.x & 63;
    int node = blockIdx.x * 2 + (wv >> 1);
    int half = wv & 1;
    int ns = wv >> 1;

    __shared__ float s_acc[2][64][CA + CB];
    __shared__ float s_sw[2];

    int beg = rowptr[node], end = rowptr[node + 1];
    float ald = al_d[node];

    float accA[CA] = {}, accB[CB] = {};
    float swsum = 0.f;

    for (int base = beg + half; base < end; base += 128) {
        int myi = base + 2 * lane;
        bool valid = myi < end;
        int sl = valid ? csr_src[myi] : 0;
        float wl = 0.f;
        if (valid) {
            float e = al_s[sl] + ald;
            e = e > 0.f ? e : NEG_SLOPE * e;
            wl = __expf(e);
        }
        swsum += wl;
        int cnt = min(64, (end - base + 1) >> 1);
        int j = 0;
        for (; j + 4 <= cnt; j += 4) {
            int ss0 = __shfl(sl, j + 0), ss1 = __shfl(sl, j + 1);
            int ss2 = __shfl(sl, j + 2), ss3 = __shfl(sl, j + 3);
            float wA0 = __shfl(wl, j + 0), wA1 = __shfl(wl, j + 1);
            float wA2 = __shfl(wl, j + 2), wA3 = __shfl(wl, j + 3);
            const _Float16* r0 = h + (size_t)ss0 * HC;
            const _Float16* r1 = h + (size_t)ss1 * HC;
            const _Float16* r2 = h + (size_t)ss2 * HC;
            const _Float16* r3 = h + (size_t)ss3 * HC;
            half4v va0 = *(const half4v*)(r0 + lane * 4);
            half4v va1 = *(const half4v*)(r1 + lane * 4);
            half4v va2 = *(const half4v*)(r2 + lane * 4);
            half4v va3 = *(const half4v*)(r3 + lane * 4);
            half2v vb0 = *(const half2v*)(r0 + 256 + lane * 2);
            half2v vb1 = *(const half2v*)(r1 + 256 + lane * 2);
            half2v vb2 = *(const half2v*)(r2 + 256 + lane * 2);
            half2v vb3 = *(const half2v*)(r3 + 256 + lane * 2);
#pragma unroll
            for (int k = 0; k < 4; ++k) {
                accA[k] = fmaf(wA0, (float)va0[k], accA[k]);
                accA[k] = fmaf(wA1, (float)va1[k], accA[k]);
                accA[k] = fmaf(wA2, (float)va2[k], accA[k]);
                accA[k] = fmaf(wA3, (float)va3[k], accA[k]);
            }
#pragma unroll
            for (int k = 0; k < 2; ++k) {
                accB[k] = fmaf(wA0, (float)vb0[k], accB[k]);
                accB[k] = fmaf(wA1, (float)vb1[k], accB[k]);
                accB[k] = fmaf(wA2, (float)vb2[k], accB[k]);
                accB[k] = fmaf(wA3, (float)vb3[k], accB[k]);
            }
        }
        for (; j < cnt; ++j) {
            int s = __shfl(sl, j);
            float aA = __shfl(wl, j);
            const _Float16* row = h + (size_t)s * HC;
            half4v va = *(const half4v*)(row + lane * 4);
            half2v vb = *(const half2v*)(row + 256 + lane * 2);
#pragma unroll
            for (int k = 0; k < 4; ++k) accA[k] = fmaf(aA, (float)va[k], accA[k]);
#pragma unroll
            for (int k = 0; k < 2; ++k) accB[k] = fmaf(aA, (float)vb[k], accB[k]);
        }
    }

#pragma unroll
    for (int off = 32; off; off >>= 1) swsum += __shfl_xor(swsum, off);

    if (half == 1) {
#pragma unroll
        for (int k = 0; k < CA; ++k) s_acc[ns][lane][k] = accA[k];
#pragma unroll
        for (int k = 0; k < CB; ++k) s_acc[ns][lane][CA + k] = accB[k];
        if (lane == 0) s_sw[ns] = swsum;
    }
    __syncthreads();
    if (half == 1) return;

#pragma unroll
    for (int k = 0; k < CA; ++k) accA[k] += s_acc[ns][lane][k];
#pragma unroll
    for (int k = 0; k < CB; ++k) accB[k] += s_acc[ns][lane][CA + k];
    float inv = 1.f / (swsum + s_sw[ns]);

    size_t obase = (size_t)node * HC;
    int cA0 = lane * CA, cB0 = 64 * CA + lane * CB;
    float4 oa;
    float t0 = accA[0] * inv + bias[cA0 + 0]; oa.x = t0 > 0.f ? t0 : 0.f;
    float t1 = accA[1] * inv + bias[cA0 + 1]; oa.y = t1 > 0.f ? t1 : 0.f;
    float t2 = accA[2] * inv + bias[cA0 + 2]; oa.z = t2 > 0.f ? t2 : 0.f;
    float t3 = accA[3] * inv + bias[cA0 + 3]; oa.w = t3 > 0.f ? t3 : 0.f;
    *(float4*)(out + obase + cA0) = oa;
    floatx2 ob;
    float u0 = accB[0] * inv + bias[cB0 + 0]; ob[0] = u0 > 0.f ? u0 : 0.f;
    float u1 = accB[1] * inv + bias[cB0 + 1]; ob[1] = u1 > 0.f ? u1 : 0.f;
    *(floatx2*)(out + obase + cB0) = ob;
}

// ---------------------------------------------------------------------- host
extern "C" void kernel_launch(void* const* d_in, const int* in_sizes, int n_in,
                              void* d_out, int out_size, void* d_ws, size_t ws_size,
                              hipStream_t stream) {
    const float* x   = (const float*)d_in[0];
    const int*   ei  = (const int*)d_in[1];
    const float* W1  = (const float*)d_in[2];
    const float* as1 = (const float*)d_in[3];
    const float* ad1 = (const float*)d_in[4];
    const float* b1  = (const float*)d_in[5];
    const float* W2  = (const float*)d_in[6];
    const float* as2 = (const float*)d_in[7];
    const float* ad2 = (const float*)d_in[8];
    const float* b2  = (const float*)d_in[9];
    float* out = (float*)d_out;

    const int N  = in_sizes[0] / 128;   // 20000
    const int E  = in_sizes[1] / 2;     // 320000
    const int ET = E + N;
    const int NB = (N + 255) / 256;     // 79 scan blocks
    const int* src = ei;
    const int* dst = ei + E;

    char* ws = (char*)d_ws;
    size_t off = 0;
    auto alloc = [&](size_t bytes) {
        void* p = ws + off;
        off = (off + bytes + 255) & ~(size_t)255;
        return p;
    };
    _Float16* xh    = (_Float16*)alloc((size_t)N * 128 * 2);
    _Float16* xagg  = (_Float16*)alloc((size_t)N * 384 * 2);
    _Float16* x2h   = (_Float16*)alloc((size_t)N * 768 * 2);
    _Float16* h2    = (_Float16*)alloc((size_t)N * 384 * 2);
    _Float16* w1t   = (_Float16*)alloc((size_t)768 * 128 * 2);
    _Float16* w2t   = (_Float16*)alloc((size_t)384 * 768 * 2);
    float* vs1  = (float*)alloc(384 * 4);
    float* vd1  = (float*)alloc(384 * 4);
    float* vs2  = (float*)alloc(768 * 4);
    float* vd2  = (float*)alloc(768 * 4);
    float* alS1 = (float*)alloc((size_t)N * 3 * 4);
    float* alD1 = (float*)alloc((size_t)N * 3 * 4);
    float* alS2 = (float*)alloc((size_t)N * 4);
    float* alD2 = (float*)alloc((size_t)N * 4);
    int* deg    = (int*)alloc((size_t)N * 4);
    int* rowptr = (int*)alloc((size_t)(N + 1) * 4);
    int* cursor = (int*)alloc((size_t)N * 4);
    int* bsum   = (int*)alloc(256 * 4);
    int* boff   = (int*)alloc(256 * 4);
    int* csrs   = (int*)alloc((size_t)ET * 4);

    // CSR by destination (shared by both layers)
    hipMemsetAsync(deg, 0, (size_t)N * 4, stream);
    k_hist<<<(ET + 255) / 256, 256, 0, stream>>>(dst, E, N, deg);
    k_scan1<<<NB, 256, 0, stream>>>(deg, bsum, N);
    k_scan2<<<1, 256, 0, stream>>>(bsum, boff, NB);
    k_scan3<<<NB, 256, 0, stream>>>(deg, boff, rowptr, cursor, N);
    k_scatter<<<(ET + 255) / 256, 256, 0, stream>>>(src, dst, E, N, cursor, csrs);

    // operand prep
    k_transpose_h<<<(128 * 768 + 255) / 256, 256, 0, stream>>>(W1, w1t, 128, 768);
    k_transpose_h<<<(768 * 384 + 255) / 256, 256, 0, stream>>>(W2, w2t, 768, 384);
    k_wv1<<<2, 256, 0, stream>>>(W1, as1, ad1, vs1, vd1);
    k_wv2<<<3, 256, 0, stream>>>(W2, as2, ad2, vs2, vd2);

    // layer 1: fused convert+logits, aggregate in input space, GEMM+bias+relu
    k_prep1<<<(N + 3) / 4, 256, 0, stream>>>(x, xh, vs1, vd1, alS1, alD1, N);
    k_aggx<<<(N + 3) / 4, 256, 0, stream>>>(xh, alS1, alD1, rowptr, csrs, xagg, N);
    dim3 g1(768 / 128, (N + 127) / 128);
    k_hgemm<_Float16, true><<<g1, 256, 0, stream>>>(xagg, w1t, b1, x2h, N, 768, 128);

    // layer 2
    k_attx2<<<(N + 3) / 4, 256, 0, stream>>>(x2h, vs2, vd2, alS2, alD2, N);
    dim3 g2(384 / 128, (N + 127) / 128);
    k_hgemm<_Float16, false><<<g2, 256, 0, stream>>>(x2h, w2t, nullptr, h2, N, 384, 768);
    k_aggw2<<<N / 2, 256, 0, stream>>>(h2, alS2, alD2, rowptr, csrs, b2, out, N);
}

// Round 9
// 211.308 us; speedup vs baseline: 1.3289x; 1.0859x over previous
//
#include <hip/hip_runtime.h>
#include <hip/hip_bf16.h>

#define NEG_SLOPE 0.2f

typedef _Float16 half8 __attribute__((ext_vector_type(8)));
typedef _Float16 half4v __attribute__((ext_vector_type(4)));
typedef _Float16 half2v __attribute__((ext_vector_type(2)));
typedef float floatx4 __attribute__((ext_vector_type(4)));
typedef float floatx2 __attribute__((ext_vector_type(2)));

// ---------------------------------------------------------------- CSR build
__global__ void k_hist(const int* __restrict__ dst, int E, int n, int* __restrict__ deg) {
    int e = blockIdx.x * blockDim.x + threadIdx.x;
    int ET = E + n;
    if (e >= ET) return;
    int d = (e < E) ? dst[e] : (e - E);   // self-loops appended
    atomicAdd(&deg[d], 1);
}

// phase 1: per-block sums (coalesced)
__global__ void k_scan1(const int* __restrict__ deg, int* __restrict__ bsum, int n) {
    __shared__ int red[256];
    int t = threadIdx.x, b = blockIdx.x;
    int i = b * 256 + t;
    red[t] = (i < n) ? deg[i] : 0;
    __syncthreads();
    for (int off = 128; off; off >>= 1) {
        if (t < off) red[t] += red[t + off];
        __syncthreads();
    }
    if (t == 0) bsum[b] = red[0];
}

// phase 2+3 fused: every block prefixes the (<=256) block sums itself, then
// does its local inclusive scan + offset -> rowptr/cursor.
__global__ void k_scan3(const int* __restrict__ deg, const int* __restrict__ bsum,
                        int nb, int* __restrict__ rowptr, int* __restrict__ cursor,
                        int n) {
    __shared__ int s[256];
    int t = threadIdx.x, b = blockIdx.x;
    // prefix the block sums (exclusive at b)
    s[t] = (t < nb) ? bsum[t] : 0;
    __syncthreads();
    for (int off = 1; off < 256; off <<= 1) {
        int v = (t >= off) ? s[t - off] : 0;
        __syncthreads();
        s[t] += v;
        __syncthreads();
    }
    int base = (b == 0) ? 0 : s[b - 1];
    __syncthreads();
    // local inclusive scan
    int i = b * 256 + t;
    int v = (i < n) ? deg[i] : 0;
    s[t] = v;
    __syncthreads();
    for (int off = 1; off < 256; off <<= 1) {
        int u = (t >= off) ? s[t - off] : 0;
        __syncthreads();
        s[t] += u;
        __syncthreads();
    }
    int incl = s[t];
    if (i < n) {
        rowptr[i] = base + incl - v;
        cursor[i] = base + incl - v;
        if (i == n - 1) rowptr[n] = base + incl;
    }
}

__global__ void k_scatter(const int* __restrict__ src, const int* __restrict__ dst,
                          int E, int n, int* __restrict__ cursor,
                          int* __restrict__ csr_src) {
    int e = blockIdx.x * blockDim.x + threadIdx.x;
    int ET = E + n;
    if (e >= ET) return;
    int s = (e < E) ? src[e] : (e - E);
    int d = (e < E) ? dst[e] : (e - E);
    int pos = atomicAdd(&cursor[d], 1);
    csr_src[pos] = s;
}

// --------------------- fused weight prep: W1t, W2t transposes + vs/vd vectors
// blocks 0..383: w1t; 384..1535: w2t; 1536..1537: wv1; 1538..1540: wv2
__global__ void k_wprep(const float* __restrict__ W1, const float* __restrict__ W2,
                        const float* __restrict__ as1, const float* __restrict__ ad1,
                        const float* __restrict__ as2, const float* __restrict__ ad2,
                        _Float16* __restrict__ w1t, _Float16* __restrict__ w2t,
                        float* __restrict__ vs1, float* __restrict__ vd1,
                        float* __restrict__ vs2, float* __restrict__ vd2) {
    int b = blockIdx.x;
    if (b < 384) {                       // W1[128][768] -> w1t[768][128]
        int i = b * 256 + threadIdx.x;   // i < 98304
        int c = i / 128, r = i % 128;
        w1t[i] = (_Float16)W1[(size_t)r * 768 + c];
    } else if (b < 1536) {               // W2[768][384] -> w2t[384][768]
        int i = (b - 384) * 256 + threadIdx.x;   // i < 294912
        int c = i / 768, r = i % 768;
        w2t[i] = (_Float16)W2[(size_t)r * 384 + c];
    } else if (b < 1538) {               // vs1/vd1 (384 outputs)
        int t = (b - 1536) * 256 + threadIdx.x;
        if (t < 384) {
            int h = t >> 7, k = t & 127;
            const float* wr = W1 + (size_t)k * 768 + h * 256;
            const float* ar = as1 + h * 256;
            const float* dr = ad1 + h * 256;
            float s = 0.f, d = 0.f;
            for (int c = 0; c < 256; ++c) { float wv = wr[c]; s += wv * ar[c]; d += wv * dr[c]; }
            vs1[t] = s; vd1[t] = d;
        }
    } else {                             // vs2/vd2 (768 outputs)
        int t = (b - 1538) * 256 + threadIdx.x;
        if (t < 768) {
            const float* wr = W2 + (size_t)t * 384;
            float s = 0.f, d = 0.f;
            for (int c = 0; c < 384; ++c) { float wv = wr[c]; s += wv * as2[c]; d += wv * ad2[c]; }
            vs2[t] = s; vd2[t] = d;
        }
    }
}

// -------------------------- fused x fp32->fp16 + layer-1 logits (one pass)
__global__ __launch_bounds__(256) void k_prep1(const float* __restrict__ x,
        _Float16* __restrict__ xh, const float* __restrict__ vs,
        const float* __restrict__ vd, float* __restrict__ al_s,
        float* __restrict__ al_d, int n) {
    int wid = (blockIdx.x * blockDim.x + threadIdx.x) >> 6;
    int lane = threadIdx.x & 63;
    if (wid >= n) return;
    float2 f = *(const float2*)(x + (size_t)wid * 128 + lane * 2);
    half2v hv; hv[0] = (_Float16)f.x; hv[1] = (_Float16)f.y;
    *(half2v*)(xh + (size_t)wid * 128 + lane * 2) = hv;
    float aS[3], aD[3];
#pragma unroll
    for (int hh = 0; hh < 3; ++hh) {
        floatx2 v = *(const floatx2*)(vs + hh * 128 + lane * 2);
        floatx2 d = *(const floatx2*)(vd + hh * 128 + lane * 2);
        aS[hh] = f.x * v[0] + f.y * v[1];
        aD[hh] = f.x * d[0] + f.y * d[1];
    }
#pragma unroll
    for (int hh = 0; hh < 3; ++hh)
#pragma unroll
        for (int off = 32; off; off >>= 1) {
            aS[hh] += __shfl_xor(aS[hh], off);
            aD[hh] += __shfl_xor(aD[hh], off);
        }
    if (lane == 0) {
#pragma unroll
        for (int hh = 0; hh < 3; ++hh) { al_s[wid * 3 + hh] = aS[hh]; al_d[wid * 3 + hh] = aD[hh]; }
    }
}

// ---------------------- layer-1 aggregation in INPUT space, inline edge exp
// No-max softmax: logits are O(+-3) by Glorot arithmetic -> exp safe; alpha
// ratio identical (validated R6-R8, absmax 2e-3). 8 edges in flight.
__global__ __launch_bounds__(256) void k_aggx(const _Float16* __restrict__ xh,
                                              const float* __restrict__ al_s,
                                              const float* __restrict__ al_d,
                                              const int* __restrict__ rowptr,
                                              const int* __restrict__ csr_src,
                                              _Float16* __restrict__ xagg,
                                              int n) {
    int wid = (blockIdx.x * blockDim.x + threadIdx.x) >> 6;
    int lane = threadIdx.x & 63;
    if (wid >= n) return;
    int beg = rowptr[wid], end = rowptr[wid + 1];
    int slot = lane >> 4;     // 0..3  (edge within group)
    int chunk = lane & 15;    // channel chunk: ch = chunk*8 .. +8

    float ald0 = al_d[wid * 3 + 0], ald1 = al_d[wid * 3 + 1], ald2 = al_d[wid * 3 + 2];

    float acc0[8] = {}, acc1[8] = {}, acc2[8] = {};
    float sw0 = 0.f, sw1 = 0.f, sw2 = 0.f;

    for (int base = beg; base < end; base += 8) {
        int eA = base + slot, eB = base + 4 + slot;
        bool vA = eA < end, vB = eB < end;
        int sA = vA ? csr_src[eA] : 0;
        int sB = vB ? csr_src[eB] : 0;
        float wA0 = 0.f, wA1 = 0.f, wA2 = 0.f, wB0 = 0.f, wB1 = 0.f, wB2 = 0.f;
        if (vA) {
            float e0 = al_s[sA * 3 + 0] + ald0; e0 = e0 > 0.f ? e0 : NEG_SLOPE * e0;
            float e1 = al_s[sA * 3 + 1] + ald1; e1 = e1 > 0.f ? e1 : NEG_SLOPE * e1;
            float e2 = al_s[sA * 3 + 2] + ald2; e2 = e2 > 0.f ? e2 : NEG_SLOPE * e2;
            wA0 = __expf(e0); wA1 = __expf(e1); wA2 = __expf(e2);
        }
        if (vB) {
            float e0 = al_s[sB * 3 + 0] + ald0; e0 = e0 > 0.f ? e0 : NEG_SLOPE * e0;
            float e1 = al_s[sB * 3 + 1] + ald1; e1 = e1 > 0.f ? e1 : NEG_SLOPE * e1;
            float e2 = al_s[sB * 3 + 2] + ald2; e2 = e2 > 0.f ? e2 : NEG_SLOPE * e2;
            wB0 = __expf(e0); wB1 = __expf(e1); wB2 = __expf(e2);
        }
        sw0 += wA0 + wB0; sw1 += wA1 + wB1; sw2 += wA2 + wB2;
        half8 xvA = *(const half8*)(xh + (size_t)sA * 128 + chunk * 8);
        half8 xvB = *(const half8*)(xh + (size_t)sB * 128 + chunk * 8);
#pragma unroll
        for (int k = 0; k < 8; ++k) {
            float fA = (float)xvA[k], fB = (float)xvB[k];
            acc0[k] = fmaf(wA0, fA, acc0[k]); acc0[k] = fmaf(wB0, fB, acc0[k]);
            acc1[k] = fmaf(wA1, fA, acc1[k]); acc1[k] = fmaf(wB1, fB, acc1[k]);
            acc2[k] = fmaf(wA2, fA, acc2[k]); acc2[k] = fmaf(wB2, fB, acc2[k]);
        }
    }
    // combine the 4 edge-slots (chunk index preserved under xor 16/32)
#pragma unroll
    for (int k = 0; k < 8; ++k) {
        acc0[k] += __shfl_xor(acc0[k], 16); acc0[k] += __shfl_xor(acc0[k], 32);
        acc1[k] += __shfl_xor(acc1[k], 16); acc1[k] += __shfl_xor(acc1[k], 32);
        acc2[k] += __shfl_xor(acc2[k], 16); acc2[k] += __shfl_xor(acc2[k], 32);
    }
    sw0 += __shfl_xor(sw0, 16); sw0 += __shfl_xor(sw0, 32);
    sw1 += __shfl_xor(sw1, 16); sw1 += __shfl_xor(sw1, 32);
    sw2 += __shfl_xor(sw2, 16); sw2 += __shfl_xor(sw2, 32);

    if (lane < 16) {
        float i0 = 1.f / sw0, i1 = 1.f / sw1, i2 = 1.f / sw2;
        _Float16* op = xagg + (size_t)wid * 384 + chunk * 8;
        half8 o0, o1, o2;
#pragma unroll
        for (int k = 0; k < 8; ++k) {
            o0[k] = (_Float16)(acc0[k] * i0);
            o1[k] = (_Float16)(acc1[k] * i1);
            o2[k] = (_Float16)(acc2[k] * i2);
        }
        *(half8*)(op + 0)   = o0;
        *(half8*)(op + 128) = o1;
        *(half8*)(op + 256) = o2;
    }
}

// ------------------------------------------------------------ fp16 MFMA GEMM
// GAT=true (layer 1): A = xagg[M][3][128], head = col block/256, epilogue
//   bias+ReLU, writes x2h fp16, AND accumulates layer-2 logits
//   alS2[row] += sum_col x2[row][col]*vs2[col] (atomics, 16-lane reduce).
// GAT=false (layer 2): plain C = A @ Bt^T, fp16 out.
__device__ __forceinline__ void gload_lds16(const _Float16* g, _Float16* l) {
    __builtin_amdgcn_global_load_lds((const __attribute__((address_space(1))) void*)g,
                                     (__attribute__((address_space(3))) void*)l,
                                     16, 0, 0);
}

template <typename OutT, bool GAT>
__global__ __launch_bounds__(256) void k_hgemm(const _Float16* __restrict__ A,
                                               const _Float16* __restrict__ Bt,
                                               const float* __restrict__ bias,
                                               const float* __restrict__ vs2,
                                               const float* __restrict__ vd2,
                                               float* __restrict__ alS2,
                                               float* __restrict__ alD2,
                                               OutT* __restrict__ C,
                                               int M, int N, int K) {
    __shared__ _Float16 lds[2 * 8192];       // [buf][A:4096|B:4096] elems (32KB)
    int t = threadIdx.x;
    int lane = t & 63, w = t >> 6;
    int wr = w >> 1, wc = w & 1;
    int lrow = lane & 15, lko = lane >> 4;
    int row0 = blockIdx.y * 128, col0 = blockIdx.x * 128;

    int sr = t & 127;
    int sko = t >> 7;
    int agr = row0 + sr; if (agr >= M) agr = M - 1;
    const _Float16* aRow;
    if constexpr (GAT) {
        int head = col0 >> 8;                    // col block -> head (256 cols/head)
        aRow = A + (size_t)agr * 384 + head * 128;
    } else {
        aRow = A + (size_t)agr * K;
    }
    const _Float16* bRow = Bt + (size_t)(col0 + sr) * K;

    floatx4 acc[4][4] = {};

    int nk = K >> 5;
#pragma unroll
    for (int s = 0; s < 2; ++s) {
        int ko = s * 2 + sko;
        gload_lds16(aRow + ko * 8, lds + s * 2048 + t * 8);
        gload_lds16(bRow + ko * 8, lds + 4096 + s * 2048 + t * 8);
    }
    __syncthreads();

    for (int ks = 0; ks < nk; ++ks) {
        int buf = ks & 1;
        if (ks + 1 < nk) {
            int kt = (ks + 1) << 5;
            _Float16* dstb = lds + (buf ^ 1) * 8192;
#pragma unroll
            for (int s = 0; s < 2; ++s) {
                int ko = s * 2 + sko;
                gload_lds16(aRow + kt + ko * 8, dstb + s * 2048 + t * 8);
                gload_lds16(bRow + kt + ko * 8, dstb + 4096 + s * 2048 + t * 8);
            }
        }
        const _Float16* base = lds + buf * 8192 + lko * 1024;
        half8 af[4], bf[4];
#pragma unroll
        for (int mi = 0; mi < 4; ++mi)
            af[mi] = *(const half8*)(base + (wr * 64 + mi * 16 + lrow) * 8);
#pragma unroll
        for (int ni = 0; ni < 4; ++ni)
            bf[ni] = *(const half8*)(base + 4096 + (wc * 64 + ni * 16 + lrow) * 8);
#pragma unroll
        for (int mi = 0; mi < 4; ++mi)
#pragma unroll
            for (int ni = 0; ni < 4; ++ni)
                acc[mi][ni] = __builtin_amdgcn_mfma_f32_16x16x32_f16(
                    af[mi], bf[ni], acc[mi][ni], 0, 0, 0);
        __syncthreads();
    }

#pragma unroll
    for (int mi = 0; mi < 4; ++mi) {
#pragma unroll
        for (int j = 0; j < 4; ++j) {
            int row = row0 + wr * 64 + mi * 16 + lko * 4 + j;
            float ps = 0.f, pd = 0.f;
#pragma unroll
            for (int ni = 0; ni < 4; ++ni) {
                int col = col0 + wc * 64 + ni * 16 + lrow;
                float v = acc[mi][ni][j];
                if constexpr (GAT) {
                    v += bias[col]; v = v > 0.f ? v : 0.f;
                    ps = fmaf(v, vs2[col], ps);
                    pd = fmaf(v, vd2[col], pd);
                }
                if (row < M) C[(size_t)row * N + col] = (OutT)v;
            }
            if constexpr (GAT) {
                if (row >= M) { ps = 0.f; pd = 0.f; }
#pragma unroll
                for (int off = 1; off < 16; off <<= 1) {
                    ps += __shfl_xor(ps, off);
                    pd += __shfl_xor(pd, off);
                }
                if (lrow == 0 && row < M) {
                    atomicAdd(&alS2[row], ps);
                    atomicAdd(&alD2[row], pd);
                }
            }
        }
    }
}

// -------------------- layer-2 gather-agg, 2 waves per node, inline edge exp
__global__ __launch_bounds__(256) void k_aggw2(const _Float16* __restrict__ h,
                                               const float* __restrict__ al_s,
                                               const float* __restrict__ al_d,
                                               const int* __restrict__ rowptr,
                                               const int* __restrict__ csr_src,
                                               const float* __restrict__ bias,
                                               float* __restrict__ out, int n) {
    constexpr int HC = 384;
    constexpr int CA = 4;
    constexpr int CB = 2;
    int wv = threadIdx.x >> 6;
    int lane = threadIdx.x & 63;
    int node = blockIdx.x * 2 + (wv >> 1);
    int half = wv & 1;
    int ns = wv >> 1;

    __shared__ float s_acc[2][64][CA + CB];
    __shared__ float s_sw[2];

    int beg = rowptr[node], end = rowptr[node + 1];
    float ald = al_d[node];

    float accA[CA] = {}, accB[CB] = {};
    float swsum = 0.f;

    for (int base = beg + half; base < end; base += 128) {
        int myi = base + 2 * lane;
        bool valid = myi < end;
        int sl = valid ? csr_src[myi] : 0;
        float wl = 0.f;
        if (valid) {
            float e = al_s[sl] + ald;
            e = e > 0.f ? e : NEG_SLOPE * e;
            wl = __expf(e);
        }
        swsum += wl;
        int cnt = min(64, (end - base + 1) >> 1);
        int j = 0;
        for (; j + 4 <= cnt; j += 4) {
            int ss0 = __shfl(sl, j + 0), ss1 = __shfl(sl, j + 1);
            int ss2 = __shfl(sl, j + 2), ss3 = __shfl(sl, j + 3);
            float wA0 = __shfl(wl, j + 0), wA1 = __shfl(wl, j + 1);
            float wA2 = __shfl(wl, j + 2), wA3 = __shfl(wl, j + 3);
            const _Float16* r0 = h + (size_t)ss0 * HC;
            const _Float16* r1 = h + (size_t)ss1 * HC;
            const _Float16* r2 = h + (size_t)ss2 * HC;
            const _Float16* r3 = h + (size_t)ss3 * HC;
            half4v va0 = *(const half4v*)(r0 + lane * 4);
            half4v va1 = *(const half4v*)(r1 + lane * 4);
            half4v va2 = *(const half4v*)(r2 + lane * 4);
            half4v va3 = *(const half4v*)(r3 + lane * 4);
            half2v vb0 = *(const half2v*)(r0 + 256 + lane * 2);
            half2v vb1 = *(const half2v*)(r1 + 256 + lane * 2);
            half2v vb2 = *(const half2v*)(r2 + 256 + lane * 2);
            half2v vb3 = *(const half2v*)(r3 + 256 + lane * 2);
#pragma unroll
            for (int k = 0; k < 4; ++k) {
                accA[k] = fmaf(wA0, (float)va0[k], accA[k]);
                accA[k] = fmaf(wA1, (float)va1[k], accA[k]);
                accA[k] = fmaf(wA2, (float)va2[k], accA[k]);
                accA[k] = fmaf(wA3, (float)va3[k], accA[k]);
            }
#pragma unroll
            for (int k = 0; k < 2; ++k) {
                accB[k] = fmaf(wA0, (float)vb0[k], accB[k]);
                accB[k] = fmaf(wA1, (float)vb1[k], accB[k]);
                accB[k] = fmaf(wA2, (float)vb2[k], accB[k]);
                accB[k] = fmaf(wA3, (float)vb3[k], accB[k]);
            }
        }
        for (; j < cnt; ++j) {
            int s = __shfl(sl, j);
            float aA = __shfl(wl, j);
            const _Float16* row = h + (size_t)s * HC;
            half4v va = *(const half4v*)(row + lane * 4);
            half2v vb = *(const half2v*)(row + 256 + lane * 2);
#pragma unroll
            for (int k = 0; k < 4; ++k) accA[k] = fmaf(aA, (float)va[k], accA[k]);
#pragma unroll
            for (int k = 0; k < 2; ++k) accB[k] = fmaf(aA, (float)vb[k], accB[k]);
        }
    }

#pragma unroll
    for (int off = 32; off; off >>= 1) swsum += __shfl_xor(swsum, off);

    if (half == 1) {
#pragma unroll
        for (int k = 0; k < CA; ++k) s_acc[ns][lane][k] = accA[k];
#pragma unroll
        for (int k = 0; k < CB; ++k) s_acc[ns][lane][CA + k] = accB[k];
        if (lane == 0) s_sw[ns] = swsum;
    }
    __syncthreads();
    if (half == 1) return;

#pragma unroll
    for (int k = 0; k < CA; ++k) accA[k] += s_acc[ns][lane][k];
#pragma unroll
    for (int k = 0; k < CB; ++k) accB[k] += s_acc[ns][lane][CA + k];
    float inv = 1.f / (swsum + s_sw[ns]);

    size_t obase = (size_t)node * HC;
    int cA0 = lane * CA, cB0 = 64 * CA + lane * CB;
    float4 oa;
    float t0 = accA[0] * inv + bias[cA0 + 0]; oa.x = t0 > 0.f ? t0 : 0.f;
    float t1 = accA[1] * inv + bias[cA0 + 1]; oa.y = t1 > 0.f ? t1 : 0.f;
    float t2 = accA[2] * inv + bias[cA0 + 2]; oa.z = t2 > 0.f ? t2 : 0.f;
    float t3 = accA[3] * inv + bias[cA0 + 3]; oa.w = t3 > 0.f ? t3 : 0.f;
    *(float4*)(out + obase + cA0) = oa;
    floatx2 ob;
    float u0 = accB[0] * inv + bias[cB0 + 0]; ob[0] = u0 > 0.f ? u0 : 0.f;
    float u1 = accB[1] * inv + bias[cB0 + 1]; ob[1] = u1 > 0.f ? u1 : 0.f;
    *(floatx2*)(out + obase + cB0) = ob;
}

// ---------------------------------------------------------------------- host
extern "C" void kernel_launch(void* const* d_in, const int* in_sizes, int n_in,
                              void* d_out, int out_size, void* d_ws, size_t ws_size,
                              hipStream_t stream) {
    const float* x   = (const float*)d_in[0];
    const int*   ei  = (const int*)d_in[1];
    const float* W1  = (const float*)d_in[2];
    const float* as1 = (const float*)d_in[3];
    const float* ad1 = (const float*)d_in[4];
    const float* b1  = (const float*)d_in[5];
    const float* W2  = (const float*)d_in[6];
    const float* as2 = (const float*)d_in[7];
    const float* ad2 = (const float*)d_in[8];
    const float* b2  = (const float*)d_in[9];
    float* out = (float*)d_out;

    const int N  = in_sizes[0] / 128;   // 20000
    const int E  = in_sizes[1] / 2;     // 320000
    const int ET = E + N;
    const int NB = (N + 255) / 256;     // 79 scan blocks
    const int* src = ei;
    const int* dst = ei + E;

    char* ws = (char*)d_ws;
    size_t off = 0;
    auto alloc = [&](size_t bytes) {
        void* p = ws + off;
        off = (off + bytes + 255) & ~(size_t)255;
        return p;
    };
    _Float16* xh    = (_Float16*)alloc((size_t)N * 128 * 2);
    _Float16* xagg  = (_Float16*)alloc((size_t)N * 384 * 2);
    _Float16* x2h   = (_Float16*)alloc((size_t)N * 768 * 2);
    _Float16* h2    = (_Float16*)alloc((size_t)N * 384 * 2);
    _Float16* w1t   = (_Float16*)alloc((size_t)768 * 128 * 2);
    _Float16* w2t   = (_Float16*)alloc((size_t)384 * 768 * 2);
    float* vs1  = (float*)alloc(384 * 4);
    float* vd1  = (float*)alloc(384 * 4);
    float* vs2  = (float*)alloc(768 * 4);
    float* vd2  = (float*)alloc(768 * 4);
    float* alS1 = (float*)alloc((size_t)N * 3 * 4);
    float* alD1 = (float*)alloc((size_t)N * 3 * 4);
    // zero-initialized region: deg | alS2 | alD2 (one memset)
    int*   deg  = (int*)alloc((size_t)N * 4);
    float* alS2 = (float*)alloc((size_t)N * 4);
    float* alD2 = (float*)alloc((size_t)N * 4);
    int* rowptr = (int*)alloc((size_t)(N + 1) * 4);
    int* cursor = (int*)alloc((size_t)N * 4);
    int* bsum   = (int*)alloc(256 * 4);
    int* csrs   = (int*)alloc((size_t)ET * 4);

    // one memset covers deg + alS2 + alD2 (contiguous, 256B-aligned gaps are
    // within the allocation and harmless to clear)
    hipMemsetAsync(deg, 0, (size_t)((char*)rowptr - (char*)deg), stream);

    // CSR by destination (shared by both layers)
    k_hist<<<(ET + 255) / 256, 256, 0, stream>>>(dst, E, N, deg);
    k_scan1<<<NB, 256, 0, stream>>>(deg, bsum, N);
    k_scan3<<<NB, 256, 0, stream>>>(deg, bsum, NB, rowptr, cursor, N);
    k_scatter<<<(ET + 255) / 256, 256, 0, stream>>>(src, dst, E, N, cursor, csrs);

    // fused weight prep (transposes + attention projection vectors)
    k_wprep<<<1541, 256, 0, stream>>>(W1, W2, as1, ad1, as2, ad2,
                                      w1t, w2t, vs1, vd1, vs2, vd2);

    // layer 1: fused convert+logits, aggregate in input space,
    // GEMM+bias+relu (+fused layer-2 logit accumulation)
    k_prep1<<<(N + 3) / 4, 256, 0, stream>>>(x, xh, vs1, vd1, alS1, alD1, N);
    k_aggx<<<(N + 3) / 4, 256, 0, stream>>>(xh, alS1, alD1, rowptr, csrs, xagg, N);
    dim3 g1(768 / 128, (N + 127) / 128);
    k_hgemm<_Float16, true><<<g1, 256, 0, stream>>>(xagg, w1t, b1, vs2, vd2,
                                                    alS2, alD2, x2h, N, 768, 128);

    // layer 2
    dim3 g2(384 / 128, (N + 127) / 128);
    k_hgemm<_Float16, false><<<g2, 256, 0, stream>>>(x2h, w2t, nullptr, nullptr,
                                                     nullptr, nullptr, nullptr,
                                                     h2, N, 384, 768);
    k_aggw2<<<N / 2, 256, 0, stream>>>(h2, alS2, alD2, rowptr, csrs, b2, out, N);
}